// Round 2
// baseline (421.488 us; speedup 1.0000x reference)
//
#include <hip/hip_runtime.h>
#include <hip/hip_bf16.h>
#include <math.h>

// Problem constants
#define BB 4
#define SS 2048
#define DD 1024
#define HH 16
#define DHE 64
#define NH (HH*DHE)   // 1024
constexpr float NEG_BIG = -1e30f; // exp(NEG_BIG) == 0, never NaN

typedef __bf16 bf16x8 __attribute__((ext_vector_type(8)));
typedef float  f32x4  __attribute__((ext_vector_type(4)));
typedef unsigned int uint32_tt;

// Async global->LDS 16B per lane: LDS dest is wave-uniform base + lane*16.
__device__ __forceinline__ void gl_lds16(const __bf16* g, __bf16* l) {
  __builtin_amdgcn_global_load_lds(
      (const __attribute__((address_space(1))) unsigned int*)g,
      (__attribute__((address_space(3))) unsigned int*)l, 16, 0, 0);
}

// Pack two fp32 -> one u32 of two bf16 (compiler fuses to v_cvt_pk_bf16_f32)
__device__ __forceinline__ unsigned pack_bf2(float lo, float hi) {
  union { __bf16 h[2]; unsigned u; } p;
  p.h[0] = (__bf16)lo; p.h[1] = (__bf16)hi;
  return p.u;
}

// ---------------------------------------------------------------------------
// Transpose 4 weight matrices fp32 [k][n] -> bf16 WT[n][k]
// ---------------------------------------------------------------------------
__global__ __launch_bounds__(256) void wtrans_k(
    const float* __restrict__ w0, const float* __restrict__ w1,
    const float* __restrict__ w2, const float* __restrict__ w3,
    __bf16* __restrict__ o0, __bf16* __restrict__ o1,
    __bf16* __restrict__ o2, __bf16* __restrict__ o3) {
  __shared__ __bf16 t[32][33];
  const float* w = blockIdx.z == 0 ? w0 : blockIdx.z == 1 ? w1 : blockIdx.z == 2 ? w2 : w3;
  __bf16*      o = blockIdx.z == 0 ? o0 : blockIdx.z == 1 ? o1 : blockIdx.z == 2 ? o2 : o3;
  int tx = threadIdx.x & 31, ty = threadIdx.x >> 5;   // 32 x 8
  int bk = blockIdx.x * 32, bn = blockIdx.y * 32;
  #pragma unroll
  for (int i = 0; i < 4; i++)
    t[ty + i * 8][tx] = (__bf16)w[(size_t)(bk + ty + i * 8) * DD + bn + tx];
  __syncthreads();
  #pragma unroll
  for (int i = 0; i < 4; i++)
    o[(size_t)(bn + ty + i * 8) * DD + bk + tx] = t[tx][ty + i * 8];
}

// ---------------------------------------------------------------------------
// Transpose V (bf16): v[s][col] -> o[col][s]
// ---------------------------------------------------------------------------
__global__ __launch_bounds__(256) void vtrans_k(
    const __bf16* __restrict__ v, __bf16* __restrict__ o) {
  __shared__ __bf16 t[32][33];
  int tx = threadIdx.x & 31, ty = threadIdx.x >> 5;
  int bs = blockIdx.x * 32, bc = blockIdx.y * 32;
  const __bf16* vz = v + (size_t)blockIdx.z * SS * NH;
  __bf16*       oz = o + (size_t)blockIdx.z * NH * SS;
  #pragma unroll
  for (int i = 0; i < 4; i++)
    t[ty + i * 8][tx] = vz[(size_t)(bs + ty + i * 8) * NH + bc + tx];
  __syncthreads();
  #pragma unroll
  for (int i = 0; i < 4; i++)
    oz[(size_t)(bc + ty + i * 8) * SS + bs + tx] = t[tx][ty + i * 8];
}

// ---------------------------------------------------------------------------
// Batched-operand pack for gemm_bt: blockIdx.z selects (A, BT, C).
// ---------------------------------------------------------------------------
struct B3 {
  const void*  a0; const void*  a1; const void*  a2;
  const __bf16* b0; const __bf16* b1; const __bf16* b2;
  void* c0; void* c1; void* c2;
};

// ---------------------------------------------------------------------------
// 128x128-tile bf16 MFMA GEMM: C[m][n] = sum_k A[m][k] * WT[n][k]
// B double-buffered via async global_load_lds issued AFTER the 2nd barrier.
// A fp32 (cvt at stage) or bf16, reg-prefetched to overlap MFMA.
// ---------------------------------------------------------------------------
template <typename AT, typename CT>
__global__ __launch_bounds__(256, 2) void gemm_bt(B3 p, size_t aoff) {
  __shared__ __bf16 As[128][40];      // padded (reg-staged)
  __shared__ __bf16 Bs[2][128][32];   // dbuf, unpadded (async-staged)
  const int z = blockIdx.z;
  const AT* __restrict__ A =
      (const AT*)(z == 0 ? p.a0 : z == 1 ? p.a1 : p.a2);
  const __bf16* __restrict__ BT = z == 0 ? p.b0 : z == 1 ? p.b1 : p.b2;
  CT* __restrict__ C = (CT*)(z == 0 ? p.c0 : z == 1 ? p.c1 : p.c2);

  const int tid  = threadIdx.x;
  const int wave = tid >> 6, lane = tid & 63;
  const int quad = lane >> 4, l16 = lane & 15;
  const int wr = (wave >> 1) * 64, wc = (wave & 1) * 64;
  const int m0 = blockIdx.y * 128, n0 = blockIdx.x * 128;

  f32x4 acc[4][4] = {};
  bf16x8 areg[2];

  auto loadA = [&](int k0) {
    #pragma unroll
    for (int i = 0; i < 2; i++) {
      int c = tid + i * 256;
      int row = c >> 2, seg = (c & 3) * 8;
      if constexpr (sizeof(AT) == 4) {
        const float* ap = (const float*)A + aoff + (size_t)(m0 + row) * DD + k0 + seg;
        f32x4 a0 = *(const f32x4*)ap;
        f32x4 a1 = *(const f32x4*)(ap + 4);
        bf16x8 av;
        #pragma unroll
        for (int j = 0; j < 4; j++) { av[j] = (__bf16)a0[j]; av[j + 4] = (__bf16)a1[j]; }
        areg[i] = av;
      } else {
        areg[i] = *(const bf16x8*)((const __bf16*)A + aoff + (size_t)(m0 + row) * DD + k0 + seg);
      }
    }
  };
  auto issueB = [&](int k0, int buf) {
    #pragma unroll
    for (int i = 0; i < 2; i++) {
      int row = wave * 16 + i * 64 + (lane >> 2);
      gl_lds16(&BT[(size_t)(n0 + row) * DD + k0 + (lane & 3) * 8],
               &Bs[buf][wave * 16 + i * 64][0]);
    }
  };

  issueB(0, 0);
  loadA(0);

  for (int it = 0; it < DD / 32; it++) {
    const int k0 = it * 32, buf = it & 1;
    __syncthreads();            // B(it) landed (vmcnt drain); As consumers done
    #pragma unroll
    for (int i = 0; i < 2; i++) {
      int c = tid + i * 256;
      *(bf16x8*)&As[c >> 2][(c & 3) * 8] = areg[i];
    }
    __syncthreads();            // As visible (nothing else in flight)
    if (it + 1 < DD / 32) {
      issueB(k0 + 32, buf ^ 1); // flies during MFMA below
      loadA(k0 + 32);           // overlaps MFMA below
    }

    bf16x8 af[4], bfr[4];
    #pragma unroll
    for (int t = 0; t < 4; t++) {
      af[t]  = *(const bf16x8*)&As[wr + t * 16 + l16][quad * 8];
      bfr[t] = *(const bf16x8*)&Bs[buf][wc + t * 16 + l16][quad * 8];
    }
    #pragma unroll
    for (int mt = 0; mt < 4; mt++)
      #pragma unroll
      for (int nt = 0; nt < 4; nt++)
        acc[mt][nt] = __builtin_amdgcn_mfma_f32_16x16x32_bf16(af[mt], bfr[nt], acc[mt][nt], 0, 0, 0);
  }

  // Epilogue: C/D layout col=lane&15, row=quad*4+r
  #pragma unroll
  for (int mt = 0; mt < 4; mt++)
    #pragma unroll
    for (int nt = 0; nt < 4; nt++)
      #pragma unroll
      for (int r = 0; r < 4; r++) {
        int row = m0 + wr + mt * 16 + quad * 4 + r;
        int col = n0 + wc + nt * 16 + l16;
        C[(size_t)row * NH + col] = (CT)acc[mt][nt][r];
      }
}

// ---------------------------------------------------------------------------
// Pipelined causal flash attention, BK=64, SWAPPED QK^T, register softmax.
//
// QK is computed as mfma(K, Q) -> S^T (A/B frag layouts are symmetric, so
// this is just an argument swap). C-layout of S^T: col(l16)=q, row(quad*4+r)
// =kpos. Each lane then holds 4 kpos scores of ONE q-column -> softmax is
// fully in registers (no Ps LDS buffer, no same-wave LDS RAW chain between
// softmax and PV). P A-fragments for PV are built with a 4-lane (stride-16)
// transpose: bf16-pack + 6 __shfl_xor(16/32/48) per tile-pair.
// Removes per tile: 16 ds_write_b16 + 2 ds_read_b128 + 2 lgkm waits from the
// serial chain; LDS 26112 -> 17408 B. prow collapses to 1 scalar per lane.
// ---------------------------------------------------------------------------
__global__ __launch_bounds__(256, 4) void attn_k(
    const __bf16* __restrict__ Q, const __bf16* __restrict__ K,
    const __bf16* __restrict__ VT, __bf16* __restrict__ O) {
  __shared__ __bf16 Ks[64][68];   // [kpos][dh]
  __shared__ __bf16 Vs[64][68];   // [dh][kpos]

  const int tid  = threadIdx.x;
  const int wave = tid >> 6, lane = tid & 63;
  const int quad = lane >> 4, l16 = lane & 15;
  const int qt = 31 - blockIdx.x;            // descending work size
  const int h = blockIdx.y, z = blockIdx.z;
  const int q0 = qt * 64;
  const int ntiles = qt + 1;                 // BK=64 tiles up to & incl. diag

  const __bf16* Qg = Q + (size_t)z * SS * NH + h * DHE;      // [s][dh] stride NH
  const __bf16* Kg = K + (size_t)z * SS * NH + h * DHE;
  const __bf16* Vg = VT + ((size_t)z * HH + h) * DHE * SS;   // [dh][s]

  // Q frags in regs, pre-scaled by 1/8 (exact in bf16). Lane l16 = q-col.
  const int qrow = q0 + wave * 16 + l16;     // this lane's q column
  bf16x8 qf[2];
  #pragma unroll
  for (int kk = 0; kk < 2; kk++) {
    bf16x8 t = *(const bf16x8*)&Qg[(size_t)qrow * NH + kk * 32 + quad * 8];
    #pragma unroll
    for (int j = 0; j < 8; j++) t[j] = (__bf16)((float)t[j] * 0.125f);
    qf[kk] = t;
  }

  bf16x8 kreg[2], vreg[2];
  auto loadKV = [&](int k0) {
    #pragma unroll
    for (int i = 0; i < 2; i++) {
      int v = tid + i * 256;   // 0..511 chunks of 8 elems = 64x64 tile
      kreg[i] = *(const bf16x8*)&Kg[(size_t)(k0 + (v >> 3)) * NH + (v & 7) * 8];
      vreg[i] = *(const bf16x8*)&Vg[(size_t)(v >> 3) * SS + k0 + (v & 7) * 8];
    }
  };
  loadKV(0);

  float prows = 0.f;             // per-lane partial sum for column q = qrow
  f32x4 oacc[4] = {};

  for (int kt = 0; kt < ntiles; kt++) {
    const int k0 = kt * 64;
    __syncthreads();                 // previous tile's LDS consumers done
    #pragma unroll
    for (int i = 0; i < 2; i++) {
      int v = tid + i * 256;
      *(bf16x8*)&Ks[v >> 3][(v & 7) * 8] = kreg[i];
      *(bf16x8*)&Vs[v >> 3][(v & 7) * 8] = vreg[i];
    }
    __syncthreads();                 // tile visible
    if (kt + 1 < ntiles) loadKV(k0 + 64);   // overlaps compute below

    const bool diag = (kt == ntiles - 1);
    // Diag tile: wave w's q-cols are q0+w*16..+15; kpos-block nt fully masked
    // iff nt > w. All bounds wave-uniform.
    const int nq  = diag ? wave + 1 : 4;          // QK blocks with live data
    const int nsm = diag ? ((wave + 2) & ~1) : 4; // processed blocks (even)
    const int nkk = nsm >> 1;                     // PV 32-wide k-chunks

    // S^T = K (Q/8)^T : sc[nt] holds kpos rows nt*16+quad*4+r, q col l16
    f32x4 sc[4] = {};
    __builtin_amdgcn_s_setprio(1);
    #pragma unroll
    for (int kk = 0; kk < 2; kk++)
      #pragma unroll
      for (int nt = 0; nt < 4; nt++)
        if (nt < nq) {
          bf16x8 kf = *(const bf16x8*)&Ks[nt * 16 + l16][kk * 32 + quad * 8];
          sc[nt] = __builtin_amdgcn_mfma_f32_16x16x32_bf16(kf, qf[kk], sc[nt], 0, 0, 0);
        }
    __builtin_amdgcn_s_setprio(0);

    // Register softmax + P->A-frag build, per pair of 16-kpos tiles.
    // Lane (quad,l16) has p for kpos = nt*16 + quad*4 + r, col q = qrow.
    // A-frag target: lane (quad',l16) needs kpos quad'*8..+7 of the pair,
    // i.e. a 4-lane transpose across lanes l16+{0,16,32,48}.
    bf16x8 pf[2];
    #pragma unroll
    for (int t = 0; t < 2; t++)
      if (t < nkk) {
        const int nt0 = 2 * t, nt1 = 2 * t + 1;
        float pA[4], pB[4];
        #pragma unroll
        for (int r = 0; r < 4; r++) {
          float v0 = sc[nt0][r], v1 = sc[nt1][r];
          if (diag) {
            const int kb = k0 + quad * 4 + r;
            if (kb + nt0 * 16 > qrow) v0 = NEG_BIG;
            if (kb + nt1 * 16 > qrow) v1 = NEG_BIG;
          }
          pA[r] = __expf(v0); pB[r] = __expf(v1);
          prows += pA[r] + pB[r];
        }
        // pack to bf16 words: a0=(kpos 4q+0,4q+1) of nt0, a1=(4q+2,4q+3); b* for nt1
        unsigned a0 = pack_bf2(pA[0], pA[1]), a1 = pack_bf2(pA[2], pA[3]);
        unsigned b0 = pack_bf2(pB[0], pB[1]), b1 = pack_bf2(pB[2], pB[3]);
        // 4-lane transpose: x = (quad odd ? a : b), y = (quad odd ? b : a)
        unsigned x0 = (quad & 1) ? a0 : b0, x1 = (quad & 1) ? a1 : b1;
        unsigned y0 = (quad & 1) ? b0 : a0, y1 = (quad & 1) ? b1 : a1;
        unsigned r16_0 = __shfl_xor((int)x0, 16), r16_1 = __shfl_xor((int)x1, 16);
        unsigned r32_0 = __shfl_xor((int)x0, 32), r32_1 = __shfl_xor((int)x1, 32);
        unsigned r48_0 = __shfl_xor((int)y0, 48), r48_1 = __shfl_xor((int)y1, 48);
        // assemble: q'0=[own a, q1.a] q'1=[q2.a, q3.a] q'2=[q0.b, q1.b] q'3=[q2.b, own b]
        unsigned w0 = quad == 0 ? a0    : quad == 1 ? r48_0 : quad == 2 ? r32_0 : r16_0;
        unsigned w1 = quad == 0 ? a1    : quad == 1 ? r48_1 : quad == 2 ? r32_1 : r16_1;
        unsigned w2 = quad == 0 ? r16_0 : quad == 1 ? r32_0 : quad == 2 ? r48_0 : b0;
        unsigned w3 = quad == 0 ? r16_1 : quad == 1 ? r32_1 : quad == 2 ? r48_1 : b1;
        union { unsigned u[4]; bf16x8 v; } asm_;
        asm_.u[0] = w0; asm_.u[1] = w1; asm_.u[2] = w2; asm_.u[3] = w3;
        pf[t] = asm_.v;
      }

    // O += P V  (P from registers; V B-frag identical to before)
    __builtin_amdgcn_s_setprio(1);
    #pragma unroll
    for (int kk = 0; kk < 2; kk++)
      if (kk < nkk) {
        #pragma unroll
        for (int dt = 0; dt < 4; dt++) {
          bf16x8 vf = *(const bf16x8*)&Vs[dt * 16 + l16][kk * 32 + quad * 8];
          oacc[dt] = __builtin_amdgcn_mfma_f32_16x16x32_bf16(pf[kk], vf, oacc[dt], 0, 0, 0);
        }
      }
    __builtin_amdgcn_s_setprio(0);
  }

  // Reduce prows across the 4 lanes holding this q-column (stride 16)
  prows += __shfl_xor(prows, 16, 64);
  prows += __shfl_xor(prows, 32, 64);
  // All lanes now hold the total for column q = q0 + wave*16 + l16.

  // Epilogue: oacc rows are q = quad*4+r -> fetch inv from lane quad*4+r
  __bf16* Og = O + (size_t)z * SS * NH + h * DHE;
  #pragma unroll
  for (int r = 0; r < 4; r++) {
    float tot = __shfl(prows, quad * 4 + r, 64);
    float inv = tot > 0.f ? 1.0f / tot : 0.f;
    int qg = q0 + wave * 16 + quad * 4 + r;
    #pragma unroll
    for (int dt = 0; dt < 4; dt++)
      Og[(size_t)qg * NH + dt * 16 + l16] = (__bf16)(oacc[dt][r] * inv);
  }
}

// ---------------------------------------------------------------------------
extern "C" void kernel_launch(void* const* d_in, const int* in_sizes, int n_in,
                              void* d_out, int out_size, void* d_ws, size_t ws_size,
                              hipStream_t stream) {
  const float* x_q = (const float*)d_in[0];
  const float* x_k = (const float*)d_in[1];
  const float* x_v = (const float*)d_in[2];
  // d_in[3] = causal mask — statically known, unused
  const float* Wq = (const float*)d_in[4];
  const float* Wk = (const float*)d_in[5];
  const float* Wv = (const float*)d_in[6];
  const float* Wo = (const float*)d_in[7];
  float* out = (float*)d_out;

  const size_t WTE = (size_t)DD * NH;           // 1M elems per weight
  const size_t PB  = (size_t)SS * NH;           // per-batch elems (2M)
  const size_t FULLB = (size_t)BB * PB;         // 8M elems

  char* ws = (char*)d_ws;
  __bf16* WqT = (__bf16*)ws;
  __bf16* WkT = WqT + WTE;
  __bf16* WvT = WkT + WTE;
  __bf16* WoT = WvT + WTE;
  __bf16* buf0 = WoT + WTE;                     // after 8 MB of weights

  wtrans_k<<<dim3(32, 32, 4), 256, 0, stream>>>(Wq, Wk, Wv, Wo, WqT, WkT, WvT, WoT);

  const size_t needFull = 4 * WTE * 2 + 4 * FULLB * 2;   // 8 MB + 64 MB
  if (ws_size >= needFull) {
    __bf16* Qb = buf0;
    __bf16* Kb = Qb + FULLB;
    __bf16* Vb = Kb + FULLB;          // natural V; dead after vtrans
    __bf16* VT = Vb + FULLB;
    __bf16* Ob = Vb;                  // alias: Ob reuses Vb slot
    B3 qkv = { x_q, x_k, x_v, WqT, WkT, WvT, Qb, Kb, Vb };
    gemm_bt<float, __bf16><<<dim3(8, 64, 3), 256, 0, stream>>>(qkv, 0);
    vtrans_k<<<dim3(SS / 32, NH / 32, BB), 256, 0, stream>>>(Vb, VT);
    attn_k<<<dim3(SS / 64, HH, BB), 256, 0, stream>>>(Qb, Kb, VT, Ob);
    B3 og = { Ob, Ob, Ob, WoT, WoT, WoT, out, out, out };
    gemm_bt<__bf16, float><<<dim3(8, 64, 1), 256, 0, stream>>>(og, 0);
  } else {
    __bf16* Qb = buf0;
    __bf16* Kb = Qb + PB;
    __bf16* Vb = Kb + PB;
    __bf16* VT = Vb + PB;
    __bf16* Ob = Vb;                  // alias
    for (int b = 0; b < BB; b++) {
      const size_t boff = (size_t)b * PB;
      B3 qkv = { x_q, x_k, x_v, WqT, WkT, WvT, Qb, Kb, Vb };
      gemm_bt<float, __bf16><<<dim3(8, 16, 3), 256, 0, stream>>>(qkv, boff);
      vtrans_k<<<dim3(SS / 32, NH / 32, 1), 256, 0, stream>>>(Vb, VT);
      attn_k<<<dim3(SS / 64, HH, 1), 256, 0, stream>>>(Qb, Kb, VT, Ob);
      B3 og = { Ob, Ob, Ob, WoT, WoT, WoT, out + boff, out + boff, out + boff };
      gemm_bt<__bf16, float><<<dim3(8, 16, 1), 256, 0, stream>>>(og, 0);
    }
  }
}

// Round 3
// 362.530 us; speedup vs baseline: 1.1626x; 1.1626x over previous
//
#include <hip/hip_runtime.h>
#include <hip/hip_bf16.h>
#include <math.h>

// Problem constants
#define BB 4
#define SS 2048
#define DD 1024
#define HH 16
#define DHE 64
#define NH (HH*DHE)   // 1024
constexpr float NEG_BIG = -1e30f; // exp(NEG_BIG) == 0, never NaN

typedef __bf16 bf16x8 __attribute__((ext_vector_type(8)));
typedef float  f32x4  __attribute__((ext_vector_type(4)));

#define WAITVM6()   asm volatile("s_waitcnt vmcnt(6)" ::: "memory")
#define WAITVM4()   asm volatile("s_waitcnt vmcnt(4)" ::: "memory")
#define WAITVM0()   asm volatile("s_waitcnt vmcnt(0)" ::: "memory")
#define WAITLGKM0() asm volatile("s_waitcnt lgkmcnt(0)" ::: "memory")
#define MEMFENCE()  asm volatile("" ::: "memory")

// Async global->LDS 16B per lane: LDS dest is wave-uniform base + lane*16.
__device__ __forceinline__ void gl_lds16(const __bf16* g, __bf16* l) {
  __builtin_amdgcn_global_load_lds(
      (const __attribute__((address_space(1))) unsigned int*)g,
      (__attribute__((address_space(3))) unsigned int*)l, 16, 0, 0);
}

// Pack two fp32 -> one u32 of two bf16
__device__ __forceinline__ unsigned pack_bf2(float lo, float hi) {
  union { __bf16 h[2]; unsigned u; } p;
  p.h[0] = (__bf16)lo; p.h[1] = (__bf16)hi;
  return p.u;
}

// ---------------------------------------------------------------------------
// Transpose 4 weight matrices fp32 [k][n] -> bf16 WT[n][k]
// ---------------------------------------------------------------------------
__global__ __launch_bounds__(256) void wtrans_k(
    const float* __restrict__ w0, const float* __restrict__ w1,
    const float* __restrict__ w2, const float* __restrict__ w3,
    __bf16* __restrict__ o0, __bf16* __restrict__ o1,
    __bf16* __restrict__ o2, __bf16* __restrict__ o3) {
  __shared__ __bf16 t[32][33];
  const float* w = blockIdx.z == 0 ? w0 : blockIdx.z == 1 ? w1 : blockIdx.z == 2 ? w2 : w3;
  __bf16*      o = blockIdx.z == 0 ? o0 : blockIdx.z == 1 ? o1 : blockIdx.z == 2 ? o2 : o3;
  int tx = threadIdx.x & 31, ty = threadIdx.x >> 5;   // 32 x 8
  int bk = blockIdx.x * 32, bn = blockIdx.y * 32;
  #pragma unroll
  for (int i = 0; i < 4; i++)
    t[ty + i * 8][tx] = (__bf16)w[(size_t)(bk + ty + i * 8) * DD + bn + tx];
  __syncthreads();
  #pragma unroll
  for (int i = 0; i < 4; i++)
    o[(size_t)(bn + ty + i * 8) * DD + bk + tx] = t[tx][ty + i * 8];
}

// ---------------------------------------------------------------------------
// Transpose V (bf16): v[s][col] -> o[col][s]
// ---------------------------------------------------------------------------
__global__ __launch_bounds__(256) void vtrans_k(
    const __bf16* __restrict__ v, __bf16* __restrict__ o) {
  __shared__ __bf16 t[32][33];
  int tx = threadIdx.x & 31, ty = threadIdx.x >> 5;
  int bs = blockIdx.x * 32, bc = blockIdx.y * 32;
  const __bf16* vz = v + (size_t)blockIdx.z * SS * NH;
  __bf16*       oz = o + (size_t)blockIdx.z * NH * SS;
  #pragma unroll
  for (int i = 0; i < 4; i++)
    t[ty + i * 8][tx] = vz[(size_t)(bs + ty + i * 8) * NH + bc + tx];
  __syncthreads();
  #pragma unroll
  for (int i = 0; i < 4; i++)
    oz[(size_t)(bc + ty + i * 8) * SS + bs + tx] = t[tx][ty + i * 8];
}

// ---------------------------------------------------------------------------
// Batched-operand pack for gemm_bt: z selects (A, BT, C).
// ---------------------------------------------------------------------------
struct B3 {
  const void*  a0; const void*  a1; const void*  a2;
  const __bf16* b0; const __bf16* b1; const __bf16* b2;
  void* c0; void* c1; void* c2;
};

// ---------------------------------------------------------------------------
// 128x128-tile bf16 MFMA GEMM with counted-vmcnt 2-deep pipeline (T3/T4-lite).
// Raw s_barrier (no vmcnt(0) drain); B staged via global_load_lds into a
// 4-buffer ring, A staged via 2-deep register slots; both issued 2 K-steps
// ahead (~1.5 iteration periods of HBM latency in flight).
// Wait math (vmcnt retires in issue order): at top of iter it, outstanding
// vmem is a suffix of [bundle(it), bundle(it+1)], |bundle| = 2 gl_lds + LA
// A-loads. s_waitcnt vmcnt(LA+2) leaves at most one full younger bundle ->
// all of bundle(it), incl. B(it)'s gl_lds, has landed. LA=4 (fp32 A) -> 6;
// LA=2 (bf16 A) -> 4. Last iter: vmcnt(0) (cheap, once).
// ---------------------------------------------------------------------------
template <typename AT, typename CT>
__global__ __launch_bounds__(256, 3) void gemm_bt(B3 p, size_t aoff) {
  __shared__ __bf16 As[128][40];      // padded (reg-staged)
  __shared__ __bf16 Bs[4][128][32];   // 4-ring, unpadded (async-staged)

  // XCD-chunked swizzle: HW maps flat%8 -> XCD; give each XCD a contiguous
  // chunk so the 8 N-blocks sharing an A-panel (consecutive flat ids) stay
  // on one XCD's L2. Bijective (nwg % 8 == 0 for all our launches).
  const unsigned nwg  = gridDim.x * gridDim.y * gridDim.z;
  const unsigned flat = blockIdx.x + gridDim.x * (blockIdx.y + gridDim.y * blockIdx.z);
  const unsigned swz  = (flat & 7) * (nwg >> 3) + (flat >> 3);
  const int bx = swz % gridDim.x;
  const unsigned rem = swz / gridDim.x;
  const int by = rem % gridDim.y;
  const int z  = rem / gridDim.y;

  const AT* __restrict__ A =
      (const AT*)(z == 0 ? p.a0 : z == 1 ? p.a1 : p.a2);
  const __bf16* __restrict__ BT = z == 0 ? p.b0 : z == 1 ? p.b1 : p.b2;
  CT* __restrict__ C = (CT*)(z == 0 ? p.c0 : z == 1 ? p.c1 : p.c2);

  const int tid  = threadIdx.x;
  const int wave = tid >> 6, lane = tid & 63;
  const int quad = lane >> 4, l16 = lane & 15;
  const int wr = (wave >> 1) * 64, wc = (wave & 1) * 64;
  const int m0 = by * 128, n0 = bx * 128;

  f32x4 acc[4][4] = {};
  bf16x8 aA[2], aB[2];    // 2-deep A slots (static indexing via unroll-by-2)

  auto loadA = [&](int k0, bf16x8 (&S)[2]) {
    #pragma unroll
    for (int i = 0; i < 2; i++) {
      int c = tid + i * 256;
      int row = c >> 2, seg = (c & 3) * 8;
      if constexpr (sizeof(AT) == 4) {
        const float* ap = (const float*)A + aoff + (size_t)(m0 + row) * DD + k0 + seg;
        f32x4 a0 = *(const f32x4*)ap;
        f32x4 a1 = *(const f32x4*)(ap + 4);
        bf16x8 av;
        #pragma unroll
        for (int j = 0; j < 4; j++) { av[j] = (__bf16)a0[j]; av[j + 4] = (__bf16)a1[j]; }
        S[i] = av;
      } else {
        S[i] = *(const bf16x8*)((const __bf16*)A + aoff + (size_t)(m0 + row) * DD + k0 + seg);
      }
    }
  };
  auto issueB = [&](int k0, int buf) {
    #pragma unroll
    for (int i = 0; i < 2; i++) {
      int row = wave * 16 + i * 64 + (lane >> 2);
      gl_lds16(&BT[(size_t)(n0 + row) * DD + k0 + (lane & 3) * 8],
               &Bs[buf][wave * 16 + i * 64][0]);
    }
  };

  auto step = [&](int it, bf16x8 (&S)[2], bool last, bool tail) {
    if (last) { WAITVM0(); }
    else if constexpr (sizeof(AT) == 4) { WAITVM6(); }
    else { WAITVM4(); }
    __builtin_amdgcn_s_barrier();          // B(it) in Bs[it&3]; As(it-1) readers done
    #pragma unroll
    for (int i = 0; i < 2; i++) {
      int c = tid + i * 256;
      *(bf16x8*)&As[c >> 2][(c & 3) * 8] = S[i];   // compiler waits vmcnt for S
    }
    WAITLGKM0();
    __builtin_amdgcn_s_barrier();          // As(it) visible
    if (!tail) {
      issueB((it + 2) * 32, (it + 2) & 3); // 2 ahead, ring slot free since it-2
      loadA((it + 2) * 32, S);             // refill just-consumed slot
    }
    const int buf = it & 3;
    bf16x8 af[4], bfr[4];
    #pragma unroll
    for (int t = 0; t < 4; t++) {
      af[t]  = *(const bf16x8*)&As[wr + t * 16 + l16][quad * 8];
      bfr[t] = *(const bf16x8*)&Bs[buf][wc + t * 16 + l16][quad * 8];
    }
    __builtin_amdgcn_s_setprio(1);
    #pragma unroll
    for (int mt = 0; mt < 4; mt++)
      #pragma unroll
      for (int nt = 0; nt < 4; nt++)
        acc[mt][nt] = __builtin_amdgcn_mfma_f32_16x16x32_bf16(af[mt], bfr[nt], acc[mt][nt], 0, 0, 0);
    __builtin_amdgcn_s_setprio(0);
  };

  // Prologue: two issue-bundles, fenced so bundle0 wholly precedes bundle1.
  issueB(0, 0);  loadA(0, aA);
  MEMFENCE();
  issueB(32, 1); loadA(32, aB);
  MEMFENCE();

  for (int it2 = 0; it2 < 15; it2++) {     // iters 0..29 steady
    step(2 * it2,     aA, false, false);
    step(2 * it2 + 1, aB, false, false);
  }
  step(30, aA, false, true);
  step(31, aB, true,  true);

  // Epilogue: C/D layout col=lane&15, row=quad*4+r
  #pragma unroll
  for (int mt = 0; mt < 4; mt++)
    #pragma unroll
    for (int nt = 0; nt < 4; nt++)
      #pragma unroll
      for (int r = 0; r < 4; r++) {
        int row = m0 + wr + mt * 16 + quad * 4 + r;
        int col = n0 + wc + nt * 16 + l16;
        C[(size_t)row * NH + col] = (CT)acc[mt][nt][r];
      }
}

// ---------------------------------------------------------------------------
// Pipelined causal flash attention, BK=64, swapped QK^T, register softmax.
// ROUND 3: triangle pairing + XCD grouping.
//  - Each block now processes TWO q-tiles, qt_hi = 31-bx and qt_lo = bx, so
//    every block does exactly 33 K-tiles: the grid is 1024 (or 256) EQUAL
//    blocks = 4/CU resident for the whole kernel. Kills the occupancy tail
//    (avg 19.5% with 1..32-tile blocks) that dominated rounds 0-2.
//  - 1D grid with XCD-grouped decode: all 16 blocks of one (h,z) — which
//    share the same 512 KB K/V panels — land on one XCD's L2
//    (HW maps flat%8 -> XCD; bijective for nwg in {256,1024}).
// ---------------------------------------------------------------------------
__global__ __launch_bounds__(256, 4) void attn_k(
    const __bf16* __restrict__ Q, const __bf16* __restrict__ K,
    const __bf16* __restrict__ VT, __bf16* __restrict__ O) {
  __shared__ __bf16 Ks[64][68];   // [kpos][dh]
  __shared__ __bf16 Vs[64][68];   // [dh][kpos]

  const int tid  = threadIdx.x;
  const int wave = tid >> 6, lane = tid & 63;
  const int quad = lane >> 4, l16 = lane & 15;

  // XCD-grouped decode: n -> (xcd, slot); 16 consecutive slots on one XCD
  // form one (h,z) group.
  const int n    = blockIdx.x;
  const int xcd  = n & 7, slot = n >> 3;
  const int gidx = xcd + 8 * (slot >> 4);   // (h,z) group id
  const int bx   = slot & 15;               // pair index 0..15
  const int h = gidx & 15, z = gidx >> 4;

  const __bf16* Qg = Q + (size_t)z * SS * NH + h * DHE;      // [s][dh] stride NH
  const __bf16* Kg = K + (size_t)z * SS * NH + h * DHE;
  const __bf16* Vg = VT + ((size_t)z * HH + h) * DHE * SS;   // [dh][s]
  __bf16*       Og = O + (size_t)z * SS * NH + h * DHE;

  bf16x8 kreg[2], vreg[2];
  auto loadKV = [&](int k0) {
    #pragma unroll
    for (int i = 0; i < 2; i++) {
      int v = tid + i * 256;   // 0..511 chunks of 8 elems = 64x64 tile
      kreg[i] = *(const bf16x8*)&Kg[(size_t)(k0 + (v >> 3)) * NH + (v & 7) * 8];
      vreg[i] = *(const bf16x8*)&Vg[(size_t)(v >> 3) * SS + k0 + (v & 7) * 8];
    }
  };

  #pragma unroll 1
  for (int seg = 0; seg < 2; seg++) {
    const int qt = seg ? bx : 31 - bx;       // {16..31} then {0..15}
    const int q0 = qt * 64;
    const int ntiles = qt + 1;

    // Q frags in regs, pre-scaled by 1/8 (exact in bf16). Lane l16 = q-col.
    const int qrow = q0 + wave * 16 + l16;
    bf16x8 qf[2];
    #pragma unroll
    for (int kk = 0; kk < 2; kk++) {
      bf16x8 t = *(const bf16x8*)&Qg[(size_t)qrow * NH + kk * 32 + quad * 8];
      #pragma unroll
      for (int j = 0; j < 8; j++) t[j] = (__bf16)((float)t[j] * 0.125f);
      qf[kk] = t;
    }

    loadKV(0);
    float prows = 0.f;             // per-lane partial sum for column q = qrow
    f32x4 oacc[4] = {};

    for (int kt = 0; kt < ntiles; kt++) {
      const int k0 = kt * 64;
      __syncthreads();                 // previous tile's LDS consumers done
      #pragma unroll
      for (int i = 0; i < 2; i++) {
        int v = tid + i * 256;
        *(bf16x8*)&Ks[v >> 3][(v & 7) * 8] = kreg[i];
        *(bf16x8*)&Vs[v >> 3][(v & 7) * 8] = vreg[i];
      }
      __syncthreads();                 // tile visible
      if (kt + 1 < ntiles) loadKV(k0 + 64);   // overlaps compute below

      const bool diag = (kt == ntiles - 1);
      const int nq  = diag ? wave + 1 : 4;          // QK blocks with live data
      const int nsm = diag ? ((wave + 2) & ~1) : 4; // processed blocks (even)
      const int nkk = nsm >> 1;                     // PV 32-wide k-chunks

      // S^T = K (Q/8)^T : sc[nt] holds kpos rows nt*16+quad*4+r, q col l16
      f32x4 sc[4] = {};
      __builtin_amdgcn_s_setprio(1);
      #pragma unroll
      for (int kk = 0; kk < 2; kk++)
        #pragma unroll
        for (int nt = 0; nt < 4; nt++)
          if (nt < nq) {
            bf16x8 kf = *(const bf16x8*)&Ks[nt * 16 + l16][kk * 32 + quad * 8];
            sc[nt] = __builtin_amdgcn_mfma_f32_16x16x32_bf16(kf, qf[kk], sc[nt], 0, 0, 0);
          }
      __builtin_amdgcn_s_setprio(0);

      // Register softmax + P->A-frag build (4-lane stride-16 transpose).
      bf16x8 pf[2];
      #pragma unroll
      for (int t = 0; t < 2; t++)
        if (t < nkk) {
          const int nt0 = 2 * t, nt1 = 2 * t + 1;
          float pA[4], pB[4];
          #pragma unroll
          for (int r = 0; r < 4; r++) {
            float v0 = sc[nt0][r], v1 = sc[nt1][r];
            if (diag) {
              const int kb = k0 + quad * 4 + r;
              if (kb + nt0 * 16 > qrow) v0 = NEG_BIG;
              if (kb + nt1 * 16 > qrow) v1 = NEG_BIG;
            }
            pA[r] = __expf(v0); pB[r] = __expf(v1);
            prows += pA[r] + pB[r];
          }
          unsigned a0 = pack_bf2(pA[0], pA[1]), a1 = pack_bf2(pA[2], pA[3]);
          unsigned b0 = pack_bf2(pB[0], pB[1]), b1 = pack_bf2(pB[2], pB[3]);
          unsigned x0 = (quad & 1) ? a0 : b0, x1 = (quad & 1) ? a1 : b1;
          unsigned y0 = (quad & 1) ? b0 : a0, y1 = (quad & 1) ? b1 : a1;
          unsigned r16_0 = __shfl_xor((int)x0, 16), r16_1 = __shfl_xor((int)x1, 16);
          unsigned r32_0 = __shfl_xor((int)x0, 32), r32_1 = __shfl_xor((int)x1, 32);
          unsigned r48_0 = __shfl_xor((int)y0, 48), r48_1 = __shfl_xor((int)y1, 48);
          unsigned w0 = quad == 0 ? a0    : quad == 1 ? r48_0 : quad == 2 ? r32_0 : r16_0;
          unsigned w1 = quad == 0 ? a1    : quad == 1 ? r48_1 : quad == 2 ? r32_1 : r16_1;
          unsigned w2 = quad == 0 ? r16_0 : quad == 1 ? r32_0 : quad == 2 ? r48_0 : b0;
          unsigned w3 = quad == 0 ? r16_1 : quad == 1 ? r32_1 : quad == 2 ? r48_1 : b1;
          union { unsigned u[4]; bf16x8 v; } asm_;
          asm_.u[0] = w0; asm_.u[1] = w1; asm_.u[2] = w2; asm_.u[3] = w3;
          pf[t] = asm_.v;
        }

      // O += P V  (P from registers)
      __builtin_amdgcn_s_setprio(1);
      #pragma unroll
      for (int kk = 0; kk < 2; kk++)
        if (kk < nkk) {
          #pragma unroll
          for (int dt = 0; dt < 4; dt++) {
            bf16x8 vf = *(const bf16x8*)&Vs[dt * 16 + l16][kk * 32 + quad * 8];
            oacc[dt] = __builtin_amdgcn_mfma_f32_16x16x32_bf16(pf[kk], vf, oacc[dt], 0, 0, 0);
          }
        }
      __builtin_amdgcn_s_setprio(0);
    }

    // Reduce prows across the 4 lanes holding this q-column (stride 16)
    prows += __shfl_xor(prows, 16, 64);
    prows += __shfl_xor(prows, 32, 64);

    // Epilogue: oacc rows are q = quad*4+r -> fetch inv from lane quad*4+r
    #pragma unroll
    for (int r = 0; r < 4; r++) {
      float tot = __shfl(prows, quad * 4 + r, 64);
      float inv = tot > 0.f ? 1.0f / tot : 0.f;
      int qg = q0 + wave * 16 + quad * 4 + r;
      #pragma unroll
      for (int dt = 0; dt < 4; dt++)
        Og[(size_t)qg * NH + dt * 16 + l16] = (__bf16)(oacc[dt][r] * inv);
    }
  }
}

// ---------------------------------------------------------------------------
extern "C" void kernel_launch(void* const* d_in, const int* in_sizes, int n_in,
                              void* d_out, int out_size, void* d_ws, size_t ws_size,
                              hipStream_t stream) {
  const float* x_q = (const float*)d_in[0];
  const float* x_k = (const float*)d_in[1];
  const float* x_v = (const float*)d_in[2];
  // d_in[3] = causal mask — statically known, unused
  const float* Wq = (const float*)d_in[4];
  const float* Wk = (const float*)d_in[5];
  const float* Wv = (const float*)d_in[6];
  const float* Wo = (const float*)d_in[7];
  float* out = (float*)d_out;

  const size_t WTE = (size_t)DD * NH;           // 1M elems per weight
  const size_t PB  = (size_t)SS * NH;           // per-batch elems (2M)
  const size_t FULLB = (size_t)BB * PB;         // 8M elems

  char* ws = (char*)d_ws;
  __bf16* WqT = (__bf16*)ws;
  __bf16* WkT = WqT + WTE;
  __bf16* WvT = WkT + WTE;
  __bf16* WoT = WvT + WTE;
  __bf16* buf0 = WoT + WTE;                     // after 8 MB of weights

  wtrans_k<<<dim3(32, 32, 4), 256, 0, stream>>>(Wq, Wk, Wv, Wo, WqT, WkT, WvT, WoT);

  const size_t needFull = 4 * WTE * 2 + 4 * FULLB * 2;   // 8 MB + 64 MB
  if (ws_size >= needFull) {
    __bf16* Qb = buf0;
    __bf16* Kb = Qb + FULLB;
    __bf16* Vb = Kb + FULLB;          // natural V; dead after vtrans
    __bf16* VT = Vb + FULLB;
    __bf16* Ob = Vb;                  // alias: Ob reuses Vb slot
    B3 qkv = { x_q, x_k, x_v, WqT, WkT, WvT, Qb, Kb, Vb };
    gemm_bt<float, __bf16><<<dim3(8, 64, 3), 256, 0, stream>>>(qkv, 0);
    vtrans_k<<<dim3(SS / 32, NH / 32, BB), 256, 0, stream>>>(Vb, VT);
    attn_k<<<dim3((SS / 128) * HH * BB), 256, 0, stream>>>(Qb, Kb, VT, Ob);
    B3 og = { Ob, Ob, Ob, WoT, WoT, WoT, out, out, out };
    gemm_bt<__bf16, float><<<dim3(8, 64, 1), 256, 0, stream>>>(og, 0);
  } else {
    __bf16* Qb = buf0;
    __bf16* Kb = Qb + PB;
    __bf16* Vb = Kb + PB;
    __bf16* VT = Vb + PB;
    __bf16* Ob = Vb;                  // alias
    for (int b = 0; b < BB; b++) {
      const size_t boff = (size_t)b * PB;
      B3 qkv = { x_q, x_k, x_v, WqT, WkT, WvT, Qb, Kb, Vb };
      gemm_bt<float, __bf16><<<dim3(8, 16, 3), 256, 0, stream>>>(qkv, boff);
      vtrans_k<<<dim3(SS / 32, NH / 32, 1), 256, 0, stream>>>(Vb, VT);
      attn_k<<<dim3((SS / 128) * HH), 256, 0, stream>>>(Qb, Kb, VT, Ob);
      B3 og = { Ob, Ob, Ob, WoT, WoT, WoT, out + boff, out + boff, out + boff };
      gemm_bt<__bf16, float><<<dim3(8, 16, 1), 256, 0, stream>>>(og, 0);
    }
  }
}

// Round 4
// 358.891 us; speedup vs baseline: 1.1744x; 1.0101x over previous
//
#include <hip/hip_runtime.h>
#include <hip/hip_bf16.h>
#include <math.h>

// Problem constants
#define BB 4
#define SS 2048
#define DD 1024
#define HH 16
#define DHE 64
#define NH (HH*DHE)   // 1024
constexpr float NEG_BIG = -1e30f; // exp(NEG_BIG) == 0, never NaN

typedef __bf16 bf16x8 __attribute__((ext_vector_type(8)));
typedef float  f32x4  __attribute__((ext_vector_type(4)));

#define WAITVM6()   asm volatile("s_waitcnt vmcnt(6)" ::: "memory")
#define WAITVM4()   asm volatile("s_waitcnt vmcnt(4)" ::: "memory")
#define WAITVM0()   asm volatile("s_waitcnt vmcnt(0)" ::: "memory")
#define WAITLGKM0() asm volatile("s_waitcnt lgkmcnt(0)" ::: "memory")
#define MEMFENCE()  asm volatile("" ::: "memory")

// Async global->LDS 16B per lane: LDS dest is wave-uniform base + lane*16.
__device__ __forceinline__ void gl_lds16(const __bf16* g, __bf16* l) {
  __builtin_amdgcn_global_load_lds(
      (const __attribute__((address_space(1))) unsigned int*)g,
      (__attribute__((address_space(3))) unsigned int*)l, 16, 0, 0);
}

// Pack two fp32 -> one u32 of two bf16
__device__ __forceinline__ unsigned pack_bf2(float lo, float hi) {
  union { __bf16 h[2]; unsigned u; } p;
  p.h[0] = (__bf16)lo; p.h[1] = (__bf16)hi;
  return p.u;
}

// ---------------------------------------------------------------------------
// Transpose 4 weight matrices fp32 [k][n] -> bf16 WT[n][k]
// ---------------------------------------------------------------------------
__global__ __launch_bounds__(256) void wtrans_k(
    const float* __restrict__ w0, const float* __restrict__ w1,
    const float* __restrict__ w2, const float* __restrict__ w3,
    __bf16* __restrict__ o0, __bf16* __restrict__ o1,
    __bf16* __restrict__ o2, __bf16* __restrict__ o3) {
  __shared__ __bf16 t[32][33];
  const float* w = blockIdx.z == 0 ? w0 : blockIdx.z == 1 ? w1 : blockIdx.z == 2 ? w2 : w3;
  __bf16*      o = blockIdx.z == 0 ? o0 : blockIdx.z == 1 ? o1 : blockIdx.z == 2 ? o2 : o3;
  int tx = threadIdx.x & 31, ty = threadIdx.x >> 5;   // 32 x 8
  int bk = blockIdx.x * 32, bn = blockIdx.y * 32;
  #pragma unroll
  for (int i = 0; i < 4; i++)
    t[ty + i * 8][tx] = (__bf16)w[(size_t)(bk + ty + i * 8) * DD + bn + tx];
  __syncthreads();
  #pragma unroll
  for (int i = 0; i < 4; i++)
    o[(size_t)(bn + ty + i * 8) * DD + bk + tx] = t[tx][ty + i * 8];
}

// ---------------------------------------------------------------------------
// Transpose V (bf16): v[s][col] -> o[col][s]
// ---------------------------------------------------------------------------
__global__ __launch_bounds__(256) void vtrans_k(
    const __bf16* __restrict__ v, __bf16* __restrict__ o) {
  __shared__ __bf16 t[32][33];
  int tx = threadIdx.x & 31, ty = threadIdx.x >> 5;
  int bs = blockIdx.x * 32, bc = blockIdx.y * 32;
  const __bf16* vz = v + (size_t)blockIdx.z * SS * NH;
  __bf16*       oz = o + (size_t)blockIdx.z * NH * SS;
  #pragma unroll
  for (int i = 0; i < 4; i++)
    t[ty + i * 8][tx] = vz[(size_t)(bs + ty + i * 8) * NH + bc + tx];
  __syncthreads();
  #pragma unroll
  for (int i = 0; i < 4; i++)
    oz[(size_t)(bc + ty + i * 8) * SS + bs + tx] = t[tx][ty + i * 8];
}

// ---------------------------------------------------------------------------
// Batched-operand pack for gemm_bt: z selects (A, BT, C).
// ---------------------------------------------------------------------------
struct B3 {
  const void*  a0; const void*  a1; const void*  a2;
  const __bf16* b0; const __bf16* b1; const __bf16* b2;
  void* c0; void* c1; void* c2;
};

// ---------------------------------------------------------------------------
// 128x128-tile bf16 MFMA GEMM with counted-vmcnt 2-deep pipeline (T3/T4-lite)
// + Bs XOR-swizzle (T2).
//
// Bs is a 64-B-stride tile: unswizzled ds_read_b128 at [row][quad*8] puts a
// quarter-wave's 16 lanes on only 2 of 8 16B-slots -> ~4x LDS serialization
// (SQ_LDS_BANK_CONFLICT 9.4M in round 3). Since global_load_lds writes
// linearly (base + lane*16), we swizzle BOTH sides with the same involution
// (rule #21): physical slot (r, s) holds logical seg s ^ ((r>>1)&3):
//  - write: lane at phys (r=lane>>2, s=lane&3) fetches global seg s^((r>>1)&3)
//  - read:  logical (row, quad) read at phys seg quad^((row>>1)&3)
// Quarter-wave slot map becomes 4*(l16&1) + quad^((l16>>1)&3): all 8 slots
// exactly 2x -> conflict-free. (As[128][40]'s 80-B stride is already free.)
// ---------------------------------------------------------------------------
template <typename AT, typename CT>
__global__ __launch_bounds__(256, 3) void gemm_bt(B3 p, size_t aoff) {
  __shared__ __bf16 As[128][40];      // padded (reg-staged)
  __shared__ __bf16 Bs[4][128][32];   // 4-ring, swizzled (async-staged)

  // XCD-chunked swizzle: HW maps flat%8 -> XCD; give each XCD a contiguous
  // chunk so the 8 N-blocks sharing an A-panel stay on one XCD's L2.
  const unsigned nwg  = gridDim.x * gridDim.y * gridDim.z;
  const unsigned flat = blockIdx.x + gridDim.x * (blockIdx.y + gridDim.y * blockIdx.z);
  const unsigned swz  = (flat & 7) * (nwg >> 3) + (flat >> 3);
  const int bx = swz % gridDim.x;
  const unsigned rem = swz / gridDim.x;
  const int by = rem % gridDim.y;
  const int z  = rem / gridDim.y;

  const AT* __restrict__ A =
      (const AT*)(z == 0 ? p.a0 : z == 1 ? p.a1 : p.a2);
  const __bf16* __restrict__ BT = z == 0 ? p.b0 : z == 1 ? p.b1 : p.b2;
  CT* __restrict__ C = (CT*)(z == 0 ? p.c0 : z == 1 ? p.c1 : p.c2);

  const int tid  = threadIdx.x;
  const int wave = tid >> 6, lane = tid & 63;
  const int quad = lane >> 4, l16 = lane & 15;
  const int wr = (wave >> 1) * 64, wc = (wave & 1) * 64;
  const int m0 = by * 128, n0 = bx * 128;

  f32x4 acc[4][4] = {};
  bf16x8 aA[2], aB[2];    // 2-deep A slots (static indexing via unroll-by-2)

  auto loadA = [&](int k0, bf16x8 (&S)[2]) {
    #pragma unroll
    for (int i = 0; i < 2; i++) {
      int c = tid + i * 256;
      int row = c >> 2, seg = (c & 3) * 8;
      if constexpr (sizeof(AT) == 4) {
        const float* ap = (const float*)A + aoff + (size_t)(m0 + row) * DD + k0 + seg;
        f32x4 a0 = *(const f32x4*)ap;
        f32x4 a1 = *(const f32x4*)(ap + 4);
        bf16x8 av;
        #pragma unroll
        for (int j = 0; j < 4; j++) { av[j] = (__bf16)a0[j]; av[j + 4] = (__bf16)a1[j]; }
        S[i] = av;
      } else {
        S[i] = *(const bf16x8*)((const __bf16*)A + aoff + (size_t)(m0 + row) * DD + k0 + seg);
      }
    }
  };
  auto issueB = [&](int k0, int buf) {
    #pragma unroll
    for (int i = 0; i < 2; i++) {
      int rr  = lane >> 2;                       // relative row 0..15
      int row = wave * 16 + i * 64 + rr;
      int seg = (lane & 3) ^ ((rr >> 1) & 3);    // logical seg for this phys slot
      gl_lds16(&BT[(size_t)(n0 + row) * DD + k0 + seg * 8],
               &Bs[buf][wave * 16 + i * 64][0]);
    }
  };

  auto step = [&](int it, bf16x8 (&S)[2], bool last, bool tail) {
    if (last) { WAITVM0(); }
    else if constexpr (sizeof(AT) == 4) { WAITVM6(); }
    else { WAITVM4(); }
    __builtin_amdgcn_s_barrier();          // B(it) in Bs[it&3]; As(it-1) readers done
    #pragma unroll
    for (int i = 0; i < 2; i++) {
      int c = tid + i * 256;
      *(bf16x8*)&As[c >> 2][(c & 3) * 8] = S[i];   // compiler waits vmcnt for S
    }
    WAITLGKM0();
    __builtin_amdgcn_s_barrier();          // As(it) visible
    if (!tail) {
      issueB((it + 2) * 32, (it + 2) & 3); // 2 ahead, ring slot free since it-2
      loadA((it + 2) * 32, S);             // refill just-consumed slot
    }
    const int buf = it & 3;
    bf16x8 af[4], bfr[4];
    #pragma unroll
    for (int t = 0; t < 4; t++) {
      af[t]  = *(const bf16x8*)&As[wr + t * 16 + l16][quad * 8];
      // swizzled read: logical (row, quad) lives at phys seg quad^((l16>>1)&3)
      bfr[t] = *(const bf16x8*)&Bs[buf][wc + t * 16 + l16][(quad ^ ((l16 >> 1) & 3)) * 8];
    }
    __builtin_amdgcn_s_setprio(1);
    #pragma unroll
    for (int mt = 0; mt < 4; mt++)
      #pragma unroll
      for (int nt = 0; nt < 4; nt++)
        acc[mt][nt] = __builtin_amdgcn_mfma_f32_16x16x32_bf16(af[mt], bfr[nt], acc[mt][nt], 0, 0, 0);
    __builtin_amdgcn_s_setprio(0);
  };

  // Prologue: two issue-bundles, fenced so bundle0 wholly precedes bundle1.
  issueB(0, 0);  loadA(0, aA);
  MEMFENCE();
  issueB(32, 1); loadA(32, aB);
  MEMFENCE();

  for (int it2 = 0; it2 < 15; it2++) {     // iters 0..29 steady
    step(2 * it2,     aA, false, false);
    step(2 * it2 + 1, aB, false, false);
  }
  step(30, aA, false, true);
  step(31, aB, true,  true);

  // Epilogue: C/D layout col=lane&15, row=quad*4+r
  #pragma unroll
  for (int mt = 0; mt < 4; mt++)
    #pragma unroll
    for (int nt = 0; nt < 4; nt++)
      #pragma unroll
      for (int r = 0; r < 4; r++) {
        int row = m0 + wr + mt * 16 + quad * 4 + r;
        int col = n0 + wc + nt * 16 + l16;
        C[(size_t)row * NH + col] = (CT)acc[mt][nt][r];
      }
}

// ---------------------------------------------------------------------------
// Pipelined causal flash attention, BK=64, swapped QK^T, register softmax,
// triangle pairing (33 tiles per block, equal-work grid) + XCD grouping.
// ---------------------------------------------------------------------------
__global__ __launch_bounds__(256, 4) void attn_k(
    const __bf16* __restrict__ Q, const __bf16* __restrict__ K,
    const __bf16* __restrict__ VT, __bf16* __restrict__ O) {
  __shared__ __bf16 Ks[64][68];   // [kpos][dh]
  __shared__ __bf16 Vs[64][68];   // [dh][kpos]

  const int tid  = threadIdx.x;
  const int wave = tid >> 6, lane = tid & 63;
  const int quad = lane >> 4, l16 = lane & 15;

  // XCD-grouped decode: n -> (xcd, slot); 16 consecutive slots on one XCD
  // form one (h,z) group.
  const int n    = blockIdx.x;
  const int xcd  = n & 7, slot = n >> 3;
  const int gidx = xcd + 8 * (slot >> 4);   // (h,z) group id
  const int bx   = slot & 15;               // pair index 0..15
  const int h = gidx & 15, z = gidx >> 4;

  const __bf16* Qg = Q + (size_t)z * SS * NH + h * DHE;      // [s][dh] stride NH
  const __bf16* Kg = K + (size_t)z * SS * NH + h * DHE;
  const __bf16* Vg = VT + ((size_t)z * HH + h) * DHE * SS;   // [dh][s]
  __bf16*       Og = O + (size_t)z * SS * NH + h * DHE;

  bf16x8 kreg[2], vreg[2];
  auto loadKV = [&](int k0) {
    #pragma unroll
    for (int i = 0; i < 2; i++) {
      int v = tid + i * 256;   // 0..511 chunks of 8 elems = 64x64 tile
      kreg[i] = *(const bf16x8*)&Kg[(size_t)(k0 + (v >> 3)) * NH + (v & 7) * 8];
      vreg[i] = *(const bf16x8*)&Vg[(size_t)(v >> 3) * SS + k0 + (v & 7) * 8];
    }
  };

  #pragma unroll 1
  for (int seg = 0; seg < 2; seg++) {
    const int qt = seg ? bx : 31 - bx;       // {16..31} then {0..15}
    const int q0 = qt * 64;
    const int ntiles = qt + 1;

    // Q frags in regs, pre-scaled by 1/8 (exact in bf16). Lane l16 = q-col.
    const int qrow = q0 + wave * 16 + l16;
    bf16x8 qf[2];
    #pragma unroll
    for (int kk = 0; kk < 2; kk++) {
      bf16x8 t = *(const bf16x8*)&Qg[(size_t)qrow * NH + kk * 32 + quad * 8];
      #pragma unroll
      for (int j = 0; j < 8; j++) t[j] = (__bf16)((float)t[j] * 0.125f);
      qf[kk] = t;
    }

    loadKV(0);
    float prows = 0.f;             // per-lane partial sum for column q = qrow
    f32x4 oacc[4] = {};

    for (int kt = 0; kt < ntiles; kt++) {
      const int k0 = kt * 64;
      __syncthreads();                 // previous tile's LDS consumers done
      #pragma unroll
      for (int i = 0; i < 2; i++) {
        int v = tid + i * 256;
        *(bf16x8*)&Ks[v >> 3][(v & 7) * 8] = kreg[i];
        *(bf16x8*)&Vs[v >> 3][(v & 7) * 8] = vreg[i];
      }
      __syncthreads();                 // tile visible
      if (kt + 1 < ntiles) loadKV(k0 + 64);   // overlaps compute below

      const bool diag = (kt == ntiles - 1);
      const int nq  = diag ? wave + 1 : 4;          // QK blocks with live data
      const int nsm = diag ? ((wave + 2) & ~1) : 4; // processed blocks (even)
      const int nkk = nsm >> 1;                     // PV 32-wide k-chunks

      // S^T = K (Q/8)^T : sc[nt] holds kpos rows nt*16+quad*4+r, q col l16
      f32x4 sc[4] = {};
      __builtin_amdgcn_s_setprio(1);
      #pragma unroll
      for (int kk = 0; kk < 2; kk++)
        #pragma unroll
        for (int nt = 0; nt < 4; nt++)
          if (nt < nq) {
            bf16x8 kf = *(const bf16x8*)&Ks[nt * 16 + l16][kk * 32 + quad * 8];
            sc[nt] = __builtin_amdgcn_mfma_f32_16x16x32_bf16(kf, qf[kk], sc[nt], 0, 0, 0);
          }
      __builtin_amdgcn_s_setprio(0);

      // Register softmax + P->A-frag build (4-lane stride-16 transpose).
      bf16x8 pf[2];
      #pragma unroll
      for (int t = 0; t < 2; t++)
        if (t < nkk) {
          const int nt0 = 2 * t, nt1 = 2 * t + 1;
          float pA[4], pB[4];
          #pragma unroll
          for (int r = 0; r < 4; r++) {
            float v0 = sc[nt0][r], v1 = sc[nt1][r];
            if (diag) {
              const int kb = k0 + quad * 4 + r;
              if (kb + nt0 * 16 > qrow) v0 = NEG_BIG;
              if (kb + nt1 * 16 > qrow) v1 = NEG_BIG;
            }
            pA[r] = __expf(v0); pB[r] = __expf(v1);
            prows += pA[r] + pB[r];
          }
          unsigned a0 = pack_bf2(pA[0], pA[1]), a1 = pack_bf2(pA[2], pA[3]);
          unsigned b0 = pack_bf2(pB[0], pB[1]), b1 = pack_bf2(pB[2], pB[3]);
          unsigned x0 = (quad & 1) ? a0 : b0, x1 = (quad & 1) ? a1 : b1;
          unsigned y0 = (quad & 1) ? b0 : a0, y1 = (quad & 1) ? b1 : a1;
          unsigned r16_0 = __shfl_xor((int)x0, 16), r16_1 = __shfl_xor((int)x1, 16);
          unsigned r32_0 = __shfl_xor((int)x0, 32), r32_1 = __shfl_xor((int)x1, 32);
          unsigned r48_0 = __shfl_xor((int)y0, 48), r48_1 = __shfl_xor((int)y1, 48);
          unsigned w0 = quad == 0 ? a0    : quad == 1 ? r48_0 : quad == 2 ? r32_0 : r16_0;
          unsigned w1 = quad == 0 ? a1    : quad == 1 ? r48_1 : quad == 2 ? r32_1 : r16_1;
          unsigned w2 = quad == 0 ? r16_0 : quad == 1 ? r32_0 : quad == 2 ? r48_0 : b0;
          unsigned w3 = quad == 0 ? r16_1 : quad == 1 ? r32_1 : quad == 2 ? r48_1 : b1;
          union { unsigned u[4]; bf16x8 v; } asm_;
          asm_.u[0] = w0; asm_.u[1] = w1; asm_.u[2] = w2; asm_.u[3] = w3;
          pf[t] = asm_.v;
        }

      // O += P V  (P from registers)
      __builtin_amdgcn_s_setprio(1);
      #pragma unroll
      for (int kk = 0; kk < 2; kk++)
        if (kk < nkk) {
          #pragma unroll
          for (int dt = 0; dt < 4; dt++) {
            bf16x8 vf = *(const bf16x8*)&Vs[dt * 16 + l16][kk * 32 + quad * 8];
            oacc[dt] = __builtin_amdgcn_mfma_f32_16x16x32_bf16(pf[kk], vf, oacc[dt], 0, 0, 0);
          }
        }
      __builtin_amdgcn_s_setprio(0);
    }

    // Reduce prows across the 4 lanes holding this q-column (stride 16)
    prows += __shfl_xor(prows, 16, 64);
    prows += __shfl_xor(prows, 32, 64);

    // Epilogue: oacc rows are q = quad*4+r -> fetch inv from lane quad*4+r
    #pragma unroll
    for (int r = 0; r < 4; r++) {
      float tot = __shfl(prows, quad * 4 + r, 64);
      float inv = tot > 0.f ? 1.0f / tot : 0.f;
      int qg = q0 + wave * 16 + quad * 4 + r;
      #pragma unroll
      for (int dt = 0; dt < 4; dt++)
        Og[(size_t)qg * NH + dt * 16 + l16] = (__bf16)(oacc[dt][r] * inv);
    }
  }
}

// ---------------------------------------------------------------------------
extern "C" void kernel_launch(void* const* d_in, const int* in_sizes, int n_in,
                              void* d_out, int out_size, void* d_ws, size_t ws_size,
                              hipStream_t stream) {
  const float* x_q = (const float*)d_in[0];
  const float* x_k = (const float*)d_in[1];
  const float* x_v = (const float*)d_in[2];
  // d_in[3] = causal mask — statically known, unused
  const float* Wq = (const float*)d_in[4];
  const float* Wk = (const float*)d_in[5];
  const float* Wv = (const float*)d_in[6];
  const float* Wo = (const float*)d_in[7];
  float* out = (float*)d_out;

  const size_t WTE = (size_t)DD * NH;           // 1M elems per weight
  const size_t PB  = (size_t)SS * NH;           // per-batch elems (2M)
  const size_t FULLB = (size_t)BB * PB;         // 8M elems

  char* ws = (char*)d_ws;
  __bf16* WqT = (__bf16*)ws;
  __bf16* WkT = WqT + WTE;
  __bf16* WvT = WkT + WTE;
  __bf16* WoT = WvT + WTE;
  __bf16* buf0 = WoT + WTE;                     // after 8 MB of weights

  wtrans_k<<<dim3(32, 32, 4), 256, 0, stream>>>(Wq, Wk, Wv, Wo, WqT, WkT, WvT, WoT);

  const size_t needFull = 4 * WTE * 2 + 4 * FULLB * 2;   // 8 MB + 64 MB
  if (ws_size >= needFull) {
    __bf16* Qb = buf0;
    __bf16* Kb = Qb + FULLB;
    __bf16* Vb = Kb + FULLB;          // natural V; dead after vtrans
    __bf16* VT = Vb + FULLB;
    __bf16* Ob = Vb;                  // alias: Ob reuses Vb slot
    B3 qkv = { x_q, x_k, x_v, WqT, WkT, WvT, Qb, Kb, Vb };
    gemm_bt<float, __bf16><<<dim3(8, 64, 3), 256, 0, stream>>>(qkv, 0);
    vtrans_k<<<dim3(SS / 32, NH / 32, BB), 256, 0, stream>>>(Vb, VT);
    attn_k<<<dim3((SS / 128) * HH * BB), 256, 0, stream>>>(Qb, Kb, VT, Ob);
    B3 og = { Ob, Ob, Ob, WoT, WoT, WoT, out, out, out };
    gemm_bt<__bf16, float><<<dim3(8, 64, 1), 256, 0, stream>>>(og, 0);
  } else {
    __bf16* Qb = buf0;
    __bf16* Kb = Qb + PB;
    __bf16* Vb = Kb + PB;
    __bf16* VT = Vb + PB;
    __bf16* Ob = Vb;                  // alias
    for (int b = 0; b < BB; b++) {
      const size_t boff = (size_t)b * PB;
      B3 qkv = { x_q, x_k, x_v, WqT, WkT, WvT, Qb, Kb, Vb };
      gemm_bt<float, __bf16><<<dim3(8, 16, 3), 256, 0, stream>>>(qkv, boff);
      vtrans_k<<<dim3(SS / 32, NH / 32, 1), 256, 0, stream>>>(Vb, VT);
      attn_k<<<dim3((SS / 128) * HH), 256, 0, stream>>>(Qb, Kb, VT, Ob);
      B3 og = { Ob, Ob, Ob, WoT, WoT, WoT, out + boff, out + boff, out + boff };
      gemm_bt<__bf16, float><<<dim3(8, 16, 1), 256, 0, stream>>>(og, 0);
    }
  }
}

// Round 5
// 350.508 us; speedup vs baseline: 1.2025x; 1.0239x over previous
//
#include <hip/hip_runtime.h>
#include <hip/hip_bf16.h>
#include <math.h>

// Problem constants
#define BB 4
#define SS 2048
#define DD 1024
#define HH 16
#define DHE 64
#define NH (HH*DHE)   // 1024
constexpr float NEG_BIG = -1e30f; // exp(NEG_BIG) == 0, never NaN

typedef __bf16 bf16x8 __attribute__((ext_vector_type(8)));
typedef float  f32x4  __attribute__((ext_vector_type(4)));

#define WAITVM6()   asm volatile("s_waitcnt vmcnt(6)" ::: "memory")
#define WAITVM4()   asm volatile("s_waitcnt vmcnt(4)" ::: "memory")
#define WAITVM0()   asm volatile("s_waitcnt vmcnt(0)" ::: "memory")
#define WAITLGKM0() asm volatile("s_waitcnt lgkmcnt(0)" ::: "memory")
#define MEMFENCE()  asm volatile("" ::: "memory")

// Async global->LDS 16B per lane: LDS dest is wave-uniform base + lane*16.
__device__ __forceinline__ void gl_lds16(const __bf16* g, __bf16* l) {
  __builtin_amdgcn_global_load_lds(
      (const __attribute__((address_space(1))) unsigned int*)g,
      (__attribute__((address_space(3))) unsigned int*)l, 16, 0, 0);
}

// Pack two fp32 -> one u32 of two bf16
__device__ __forceinline__ unsigned pack_bf2(float lo, float hi) {
  union { __bf16 h[2]; unsigned u; } p;
  p.h[0] = (__bf16)lo; p.h[1] = (__bf16)hi;
  return p.u;
}

// ---------------------------------------------------------------------------
// Transpose 4 weight matrices fp32 [k][n] -> bf16 WT[n][k]
// ---------------------------------------------------------------------------
__global__ __launch_bounds__(256) void wtrans_k(
    const float* __restrict__ w0, const float* __restrict__ w1,
    const float* __restrict__ w2, const float* __restrict__ w3,
    __bf16* __restrict__ o0, __bf16* __restrict__ o1,
    __bf16* __restrict__ o2, __bf16* __restrict__ o3) {
  __shared__ __bf16 t[32][33];
  const float* w = blockIdx.z == 0 ? w0 : blockIdx.z == 1 ? w1 : blockIdx.z == 2 ? w2 : w3;
  __bf16*      o = blockIdx.z == 0 ? o0 : blockIdx.z == 1 ? o1 : blockIdx.z == 2 ? o2 : o3;
  int tx = threadIdx.x & 31, ty = threadIdx.x >> 5;   // 32 x 8
  int bk = blockIdx.x * 32, bn = blockIdx.y * 32;
  #pragma unroll
  for (int i = 0; i < 4; i++)
    t[ty + i * 8][tx] = (__bf16)w[(size_t)(bk + ty + i * 8) * DD + bn + tx];
  __syncthreads();
  #pragma unroll
  for (int i = 0; i < 4; i++)
    o[(size_t)(bn + ty + i * 8) * DD + bk + tx] = t[tx][ty + i * 8];
}

// ---------------------------------------------------------------------------
// Transpose V (bf16): v[s][col] -> o[col][s]
// ---------------------------------------------------------------------------
__global__ __launch_bounds__(256) void vtrans_k(
    const __bf16* __restrict__ v, __bf16* __restrict__ o) {
  __shared__ __bf16 t[32][33];
  int tx = threadIdx.x & 31, ty = threadIdx.x >> 5;
  int bs = blockIdx.x * 32, bc = blockIdx.y * 32;
  const __bf16* vz = v + (size_t)blockIdx.z * SS * NH;
  __bf16*       oz = o + (size_t)blockIdx.z * NH * SS;
  #pragma unroll
  for (int i = 0; i < 4; i++)
    t[ty + i * 8][tx] = vz[(size_t)(bs + ty + i * 8) * NH + bc + tx];
  __syncthreads();
  #pragma unroll
  for (int i = 0; i < 4; i++)
    oz[(size_t)(bc + ty + i * 8) * SS + bs + tx] = t[tx][ty + i * 8];
}

// ---------------------------------------------------------------------------
// Batched-operand pack for gemm_bt: z selects (A, BT, C).
// ---------------------------------------------------------------------------
struct B3 {
  const void*  a0; const void*  a1; const void*  a2;
  const __bf16* b0; const __bf16* b1; const __bf16* b2;
  void* c0; void* c1; void* c2;
};

// A staging slot: RAW loaded data only (no cvt at load-issue!).
// fp32 path keeps the two f32x4 halves; cvt is deferred to the As-write,
// by which point the top-of-iter vmcnt has already retired these loads.
template <typename AT> struct AStage;
template <> struct AStage<float>  { f32x4 d[2][2]; };   // [i][half]
template <> struct AStage<__bf16> { bf16x8 d[2]; };     // [i]

// ---------------------------------------------------------------------------
// 128x128-tile bf16 MFMA GEMM, counted-vmcnt 2-deep pipeline + Bs XOR-swizzle.
//
// ROUND 5 FIX: round-3/4's loadA converted fp32->bf16 AT LOAD-ISSUE time,
// forcing the compiler to insert s_waitcnt for loads issued ~10 instructions
// earlier -> a full HBM-latency stall inside EVERY iteration (the counters'
// flat profile: MfmaUtil 15%, VALUBusy 10%, HBM 11%, all idle). The A
// prefetch was fictional. Now loadA stores raw f32x4 (+16 VGPR) and the
// cvt happens at the As-write site, where the loads are 2 iterations old
// and already retired by the top-of-iter vmcnt(6).
// ---------------------------------------------------------------------------
template <typename AT, typename CT>
__global__ __launch_bounds__(256, 3) void gemm_bt(B3 p, size_t aoff) {
  __shared__ __bf16 As[128][40];      // padded (reg-staged)
  __shared__ __bf16 Bs[4][128][32];   // 4-ring, swizzled (async-staged)

  // XCD-chunked swizzle: HW maps flat%8 -> XCD; give each XCD a contiguous
  // chunk so the 8 N-blocks sharing an A-panel stay on one XCD's L2.
  const unsigned nwg  = gridDim.x * gridDim.y * gridDim.z;
  const unsigned flat = blockIdx.x + gridDim.x * (blockIdx.y + gridDim.y * blockIdx.z);
  const unsigned swz  = (flat & 7) * (nwg >> 3) + (flat >> 3);
  const int bx = swz % gridDim.x;
  const unsigned rem = swz / gridDim.x;
  const int by = rem % gridDim.y;
  const int z  = rem / gridDim.y;

  const AT* __restrict__ A =
      (const AT*)(z == 0 ? p.a0 : z == 1 ? p.a1 : p.a2);
  const __bf16* __restrict__ BT = z == 0 ? p.b0 : z == 1 ? p.b1 : p.b2;
  CT* __restrict__ C = (CT*)(z == 0 ? p.c0 : z == 1 ? p.c1 : p.c2);

  const int tid  = threadIdx.x;
  const int wave = tid >> 6, lane = tid & 63;
  const int quad = lane >> 4, l16 = lane & 15;
  const int wr = (wave >> 1) * 64, wc = (wave & 1) * 64;
  const int m0 = by * 128, n0 = bx * 128;

  f32x4 acc[4][4] = {};
  AStage<AT> aA, aB;      // 2-deep A slots, raw data (static indexing)

  auto loadA = [&](int k0, AStage<AT>& S) {
    #pragma unroll
    for (int i = 0; i < 2; i++) {
      int c = tid + i * 256;
      int row = c >> 2, seg = (c & 3) * 8;
      if constexpr (sizeof(AT) == 4) {
        const float* ap = (const float*)A + aoff + (size_t)(m0 + row) * DD + k0 + seg;
        S.d[i][0] = *(const f32x4*)ap;        // raw loads only — no cvt here
        S.d[i][1] = *(const f32x4*)(ap + 4);
      } else {
        S.d[i] = *(const bf16x8*)((const __bf16*)A + aoff + (size_t)(m0 + row) * DD + k0 + seg);
      }
    }
  };
  auto issueB = [&](int k0, int buf) {
    #pragma unroll
    for (int i = 0; i < 2; i++) {
      int rr  = lane >> 2;                       // relative row 0..15
      int row = wave * 16 + i * 64 + rr;
      int seg = (lane & 3) ^ ((rr >> 1) & 3);    // logical seg for this phys slot
      gl_lds16(&BT[(size_t)(n0 + row) * DD + k0 + seg * 8],
               &Bs[buf][wave * 16 + i * 64][0]);
    }
  };

  auto step = [&](int it, AStage<AT>& S, bool last, bool tail) {
    if (last) { WAITVM0(); }
    else if constexpr (sizeof(AT) == 4) { WAITVM6(); }
    else { WAITVM4(); }
    __builtin_amdgcn_s_barrier();          // B(it) in Bs[it&3]; As(it-1) readers done
    #pragma unroll
    for (int i = 0; i < 2; i++) {
      int c = tid + i * 256;
      bf16x8 av;
      if constexpr (sizeof(AT) == 4) {
        #pragma unroll
        for (int j = 0; j < 4; j++) {
          av[j]     = (__bf16)S.d[i][0][j];  // cvt HERE: loads are 2 iters old,
          av[j + 4] = (__bf16)S.d[i][1][j];  // already retired by vmcnt above
        }
      } else {
        av = S.d[i];
      }
      *(bf16x8*)&As[c >> 2][(c & 3) * 8] = av;
    }
    WAITLGKM0();
    __builtin_amdgcn_s_barrier();          // As(it) visible
    if (!tail) {
      issueB((it + 2) * 32, (it + 2) & 3); // 2 ahead, ring slot free since it-2
      loadA((it + 2) * 32, S);             // raw loads, genuinely async now
    }
    const int buf = it & 3;
    bf16x8 af[4], bfr[4];
    #pragma unroll
    for (int t = 0; t < 4; t++) {
      af[t]  = *(const bf16x8*)&As[wr + t * 16 + l16][quad * 8];
      // swizzled read: logical (row, quad) lives at phys seg quad^((l16>>1)&3)
      bfr[t] = *(const bf16x8*)&Bs[buf][wc + t * 16 + l16][(quad ^ ((l16 >> 1) & 3)) * 8];
    }
    __builtin_amdgcn_s_setprio(1);
    #pragma unroll
    for (int mt = 0; mt < 4; mt++)
      #pragma unroll
      for (int nt = 0; nt < 4; nt++)
        acc[mt][nt] = __builtin_amdgcn_mfma_f32_16x16x32_bf16(af[mt], bfr[nt], acc[mt][nt], 0, 0, 0);
    __builtin_amdgcn_s_setprio(0);
  };

  // Prologue: two issue-bundles, fenced so bundle0 wholly precedes bundle1.
  issueB(0, 0);  loadA(0, aA);
  MEMFENCE();
  issueB(32, 1); loadA(32, aB);
  MEMFENCE();

  for (int it2 = 0; it2 < 15; it2++) {     // iters 0..29 steady
    step(2 * it2,     aA, false, false);
    step(2 * it2 + 1, aB, false, false);
  }
  step(30, aA, false, true);
  step(31, aB, true,  true);

  // Epilogue: C/D layout col=lane&15, row=quad*4+r
  #pragma unroll
  for (int mt = 0; mt < 4; mt++)
    #pragma unroll
    for (int nt = 0; nt < 4; nt++)
      #pragma unroll
      for (int r = 0; r < 4; r++) {
        int row = m0 + wr + mt * 16 + quad * 4 + r;
        int col = n0 + wc + nt * 16 + l16;
        C[(size_t)row * NH + col] = (CT)acc[mt][nt][r];
      }
}

// ---------------------------------------------------------------------------
// Pipelined causal flash attention, BK=64, swapped QK^T, register softmax,
// triangle pairing (33 tiles per block, equal-work grid) + XCD grouping.
// ---------------------------------------------------------------------------
__global__ __launch_bounds__(256, 4) void attn_k(
    const __bf16* __restrict__ Q, const __bf16* __restrict__ K,
    const __bf16* __restrict__ VT, __bf16* __restrict__ O) {
  __shared__ __bf16 Ks[64][68];   // [kpos][dh]
  __shared__ __bf16 Vs[64][68];   // [dh][kpos]

  const int tid  = threadIdx.x;
  const int wave = tid >> 6, lane = tid & 63;
  const int quad = lane >> 4, l16 = lane & 15;

  // XCD-grouped decode: n -> (xcd, slot); 16 consecutive slots on one XCD
  // form one (h,z) group.
  const int n    = blockIdx.x;
  const int xcd  = n & 7, slot = n >> 3;
  const int gidx = xcd + 8 * (slot >> 4);   // (h,z) group id
  const int bx   = slot & 15;               // pair index 0..15
  const int h = gidx & 15, z = gidx >> 4;

  const __bf16* Qg = Q + (size_t)z * SS * NH + h * DHE;      // [s][dh] stride NH
  const __bf16* Kg = K + (size_t)z * SS * NH + h * DHE;
  const __bf16* Vg = VT + ((size_t)z * HH + h) * DHE * SS;   // [dh][s]
  __bf16*       Og = O + (size_t)z * SS * NH + h * DHE;

  bf16x8 kreg[2], vreg[2];
  auto loadKV = [&](int k0) {
    #pragma unroll
    for (int i = 0; i < 2; i++) {
      int v = tid + i * 256;   // 0..511 chunks of 8 elems = 64x64 tile
      kreg[i] = *(const bf16x8*)&Kg[(size_t)(k0 + (v >> 3)) * NH + (v & 7) * 8];
      vreg[i] = *(const bf16x8*)&Vg[(size_t)(v >> 3) * SS + k0 + (v & 7) * 8];
    }
  };

  #pragma unroll 1
  for (int seg = 0; seg < 2; seg++) {
    const int qt = seg ? bx : 31 - bx;       // {16..31} then {0..15}
    const int q0 = qt * 64;
    const int ntiles = qt + 1;

    // Q frags in regs, pre-scaled by 1/8 (exact in bf16). Lane l16 = q-col.
    const int qrow = q0 + wave * 16 + l16;
    bf16x8 qf[2];
    #pragma unroll
    for (int kk = 0; kk < 2; kk++) {
      bf16x8 t = *(const bf16x8*)&Qg[(size_t)qrow * NH + kk * 32 + quad * 8];
      #pragma unroll
      for (int j = 0; j < 8; j++) t[j] = (__bf16)((float)t[j] * 0.125f);
      qf[kk] = t;
    }

    loadKV(0);
    float prows = 0.f;             // per-lane partial sum for column q = qrow
    f32x4 oacc[4] = {};

    for (int kt = 0; kt < ntiles; kt++) {
      const int k0 = kt * 64;
      __syncthreads();                 // previous tile's LDS consumers done
      #pragma unroll
      for (int i = 0; i < 2; i++) {
        int v = tid + i * 256;
        *(bf16x8*)&Ks[v >> 3][(v & 7) * 8] = kreg[i];
        *(bf16x8*)&Vs[v >> 3][(v & 7) * 8] = vreg[i];
      }
      __syncthreads();                 // tile visible
      if (kt + 1 < ntiles) loadKV(k0 + 64);   // overlaps compute below

      const bool diag = (kt == ntiles - 1);
      const int nq  = diag ? wave + 1 : 4;          // QK blocks with live data
      const int nsm = diag ? ((wave + 2) & ~1) : 4; // processed blocks (even)
      const int nkk = nsm >> 1;                     // PV 32-wide k-chunks

      // S^T = K (Q/8)^T : sc[nt] holds kpos rows nt*16+quad*4+r, q col l16
      f32x4 sc[4] = {};
      __builtin_amdgcn_s_setprio(1);
      #pragma unroll
      for (int kk = 0; kk < 2; kk++)
        #pragma unroll
        for (int nt = 0; nt < 4; nt++)
          if (nt < nq) {
            bf16x8 kf = *(const bf16x8*)&Ks[nt * 16 + l16][kk * 32 + quad * 8];
            sc[nt] = __builtin_amdgcn_mfma_f32_16x16x32_bf16(kf, qf[kk], sc[nt], 0, 0, 0);
          }
      __builtin_amdgcn_s_setprio(0);

      // Register softmax + P->A-frag build (4-lane stride-16 transpose).
      bf16x8 pf[2];
      #pragma unroll
      for (int t = 0; t < 2; t++)
        if (t < nkk) {
          const int nt0 = 2 * t, nt1 = 2 * t + 1;
          float pA[4], pB[4];
          #pragma unroll
          for (int r = 0; r < 4; r++) {
            float v0 = sc[nt0][r], v1 = sc[nt1][r];
            if (diag) {
              const int kb = k0 + quad * 4 + r;
              if (kb + nt0 * 16 > qrow) v0 = NEG_BIG;
              if (kb + nt1 * 16 > qrow) v1 = NEG_BIG;
            }
            pA[r] = __expf(v0); pB[r] = __expf(v1);
            prows += pA[r] + pB[r];
          }
          unsigned a0 = pack_bf2(pA[0], pA[1]), a1 = pack_bf2(pA[2], pA[3]);
          unsigned b0 = pack_bf2(pB[0], pB[1]), b1 = pack_bf2(pB[2], pB[3]);
          unsigned x0 = (quad & 1) ? a0 : b0, x1 = (quad & 1) ? a1 : b1;
          unsigned y0 = (quad & 1) ? b0 : a0, y1 = (quad & 1) ? b1 : a1;
          unsigned r16_0 = __shfl_xor((int)x0, 16), r16_1 = __shfl_xor((int)x1, 16);
          unsigned r32_0 = __shfl_xor((int)x0, 32), r32_1 = __shfl_xor((int)x1, 32);
          unsigned r48_0 = __shfl_xor((int)y0, 48), r48_1 = __shfl_xor((int)y1, 48);
          unsigned w0 = quad == 0 ? a0    : quad == 1 ? r48_0 : quad == 2 ? r32_0 : r16_0;
          unsigned w1 = quad == 0 ? a1    : quad == 1 ? r48_1 : quad == 2 ? r32_1 : r16_1;
          unsigned w2 = quad == 0 ? r16_0 : quad == 1 ? r32_0 : quad == 2 ? r48_0 : b0;
          unsigned w3 = quad == 0 ? r16_1 : quad == 1 ? r32_1 : quad == 2 ? r48_1 : b1;
          union { unsigned u[4]; bf16x8 v; } asm_;
          asm_.u[0] = w0; asm_.u[1] = w1; asm_.u[2] = w2; asm_.u[3] = w3;
          pf[t] = asm_.v;
        }

      // O += P V  (P from registers)
      __builtin_amdgcn_s_setprio(1);
      #pragma unroll
      for (int kk = 0; kk < 2; kk++)
        if (kk < nkk) {
          #pragma unroll
          for (int dt = 0; dt < 4; dt++) {
            bf16x8 vf = *(const bf16x8*)&Vs[dt * 16 + l16][kk * 32 + quad * 8];
            oacc[dt] = __builtin_amdgcn_mfma_f32_16x16x32_bf16(pf[kk], vf, oacc[dt], 0, 0, 0);
          }
        }
      __builtin_amdgcn_s_setprio(0);
    }

    // Reduce prows across the 4 lanes holding this q-column (stride 16)
    prows += __shfl_xor(prows, 16, 64);
    prows += __shfl_xor(prows, 32, 64);

    // Epilogue: oacc rows are q = quad*4+r -> fetch inv from lane quad*4+r
    #pragma unroll
    for (int r = 0; r < 4; r++) {
      float tot = __shfl(prows, quad * 4 + r, 64);
      float inv = tot > 0.f ? 1.0f / tot : 0.f;
      int qg = q0 + wave * 16 + quad * 4 + r;
      #pragma unroll
      for (int dt = 0; dt < 4; dt++)
        Og[(size_t)qg * NH + dt * 16 + l16] = (__bf16)(oacc[dt][r] * inv);
    }
  }
}

// ---------------------------------------------------------------------------
extern "C" void kernel_launch(void* const* d_in, const int* in_sizes, int n_in,
                              void* d_out, int out_size, void* d_ws, size_t ws_size,
                              hipStream_t stream) {
  const float* x_q = (const float*)d_in[0];
  const float* x_k = (const float*)d_in[1];
  const float* x_v = (const float*)d_in[2];
  // d_in[3] = causal mask — statically known, unused
  const float* Wq = (const float*)d_in[4];
  const float* Wk = (const float*)d_in[5];
  const float* Wv = (const float*)d_in[6];
  const float* Wo = (const float*)d_in[7];
  float* out = (float*)d_out;

  const size_t WTE = (size_t)DD * NH;           // 1M elems per weight
  const size_t PB  = (size_t)SS * NH;           // per-batch elems (2M)
  const size_t FULLB = (size_t)BB * PB;         // 8M elems

  char* ws = (char*)d_ws;
  __bf16* WqT = (__bf16*)ws;
  __bf16* WkT = WqT + WTE;
  __bf16* WvT = WkT + WTE;
  __bf16* WoT = WvT + WTE;
  __bf16* buf0 = WoT + WTE;                     // after 8 MB of weights

  wtrans_k<<<dim3(32, 32, 4), 256, 0, stream>>>(Wq, Wk, Wv, Wo, WqT, WkT, WvT, WoT);

  const size_t needFull = 4 * WTE * 2 + 4 * FULLB * 2;   // 8 MB + 64 MB
  if (ws_size >= needFull) {
    __bf16* Qb = buf0;
    __bf16* Kb = Qb + FULLB;
    __bf16* Vb = Kb + FULLB;          // natural V; dead after vtrans
    __bf16* VT = Vb + FULLB;
    __bf16* Ob = Vb;                  // alias: Ob reuses Vb slot
    B3 qkv = { x_q, x_k, x_v, WqT, WkT, WvT, Qb, Kb, Vb };
    gemm_bt<float, __bf16><<<dim3(8, 64, 3), 256, 0, stream>>>(qkv, 0);
    vtrans_k<<<dim3(SS / 32, NH / 32, BB), 256, 0, stream>>>(Vb, VT);
    attn_k<<<dim3((SS / 128) * HH * BB), 256, 0, stream>>>(Qb, Kb, VT, Ob);
    B3 og = { Ob, Ob, Ob, WoT, WoT, WoT, out, out, out };
    gemm_bt<__bf16, float><<<dim3(8, 64, 1), 256, 0, stream>>>(og, 0);
  } else {
    __bf16* Qb = buf0;
    __bf16* Kb = Qb + PB;
    __bf16* Vb = Kb + PB;
    __bf16* VT = Vb + PB;
    __bf16* Ob = Vb;                  // alias
    for (int b = 0; b < BB; b++) {
      const size_t boff = (size_t)b * PB;
      B3 qkv = { x_q, x_k, x_v, WqT, WkT, WvT, Qb, Kb, Vb };
      gemm_bt<float, __bf16><<<dim3(8, 16, 3), 256, 0, stream>>>(qkv, boff);
      vtrans_k<<<dim3(SS / 32, NH / 32, 1), 256, 0, stream>>>(Vb, VT);
      attn_k<<<dim3((SS / 128) * HH), 256, 0, stream>>>(Qb, Kb, VT, Ob);
      B3 og = { Ob, Ob, Ob, WoT, WoT, WoT, out + boff, out + boff, out + boff };
      gemm_bt<__bf16, float><<<dim3(8, 16, 1), 256, 0, stream>>>(og, 0);
    }
  }
}

// Round 6
// 334.247 us; speedup vs baseline: 1.2610x; 1.0486x over previous
//
#include <hip/hip_runtime.h>
#include <hip/hip_bf16.h>
#include <math.h>

// Problem constants
#define BB 4
#define SS 2048
#define DD 1024
#define HH 16
#define DHE 64
#define NH (HH*DHE)   // 1024
constexpr float NEG_BIG = -1e30f; // exp(NEG_BIG) == 0, never NaN

typedef __bf16 bf16x8 __attribute__((ext_vector_type(8)));
typedef float  f32x4  __attribute__((ext_vector_type(4)));

#define WAITVM6()   asm volatile("s_waitcnt vmcnt(6)" ::: "memory")
#define WAITVM4()   asm volatile("s_waitcnt vmcnt(4)" ::: "memory")
#define WAITVM0()   asm volatile("s_waitcnt vmcnt(0)" ::: "memory")
#define WAITLGKM0() asm volatile("s_waitcnt lgkmcnt(0)" ::: "memory")
#define MEMFENCE()  asm volatile("" ::: "memory")

// Async global->LDS 16B per lane: LDS dest is wave-uniform base + lane*16.
__device__ __forceinline__ void gl_lds16(const __bf16* g, __bf16* l) {
  __builtin_amdgcn_global_load_lds(
      (const __attribute__((address_space(1))) unsigned int*)g,
      (__attribute__((address_space(3))) unsigned int*)l, 16, 0, 0);
}

// Pack two fp32 -> one u32 of two bf16
__device__ __forceinline__ unsigned pack_bf2(float lo, float hi) {
  union { __bf16 h[2]; unsigned u; } p;
  p.h[0] = (__bf16)lo; p.h[1] = (__bf16)hi;
  return p.u;
}

// ---------------------------------------------------------------------------
// fp32 -> bf16 bulk convert (3 tensors, one launch). Memory-bound: 2KB/wave
// contiguous reads, 1KB writes.
// ---------------------------------------------------------------------------
__global__ __launch_bounds__(256) void cvt_k(
    const float* __restrict__ x0, const float* __restrict__ x1,
    const float* __restrict__ x2,
    __bf16* __restrict__ o0, __bf16* __restrict__ o1, __bf16* __restrict__ o2) {
  const float* x = blockIdx.z == 0 ? x0 : blockIdx.z == 1 ? x1 : x2;
  __bf16*      o = blockIdx.z == 0 ? o0 : blockIdx.z == 1 ? o1 : o2;
  const size_t n8 = (size_t)BB * SS * DD / 8;   // 1,048,576 groups of 8
  for (size_t i = (size_t)blockIdx.x * 256 + threadIdx.x; i < n8;
       i += (size_t)gridDim.x * 256) {
    f32x4 a = *(const f32x4*)(x + i * 8);
    f32x4 b = *(const f32x4*)(x + i * 8 + 4);
    bf16x8 v;
    #pragma unroll
    for (int j = 0; j < 4; j++) { v[j] = (__bf16)a[j]; v[j + 4] = (__bf16)b[j]; }
    *(bf16x8*)(o + i * 8) = v;
  }
}

// ---------------------------------------------------------------------------
// Transpose 4 weight matrices fp32 [k][n] -> bf16 WT[n][k]
// ---------------------------------------------------------------------------
__global__ __launch_bounds__(256) void wtrans_k(
    const float* __restrict__ w0, const float* __restrict__ w1,
    const float* __restrict__ w2, const float* __restrict__ w3,
    __bf16* __restrict__ o0, __bf16* __restrict__ o1,
    __bf16* __restrict__ o2, __bf16* __restrict__ o3) {
  __shared__ __bf16 t[32][33];
  const float* w = blockIdx.z == 0 ? w0 : blockIdx.z == 1 ? w1 : blockIdx.z == 2 ? w2 : w3;
  __bf16*      o = blockIdx.z == 0 ? o0 : blockIdx.z == 1 ? o1 : blockIdx.z == 2 ? o2 : o3;
  int tx = threadIdx.x & 31, ty = threadIdx.x >> 5;   // 32 x 8
  int bk = blockIdx.x * 32, bn = blockIdx.y * 32;
  #pragma unroll
  for (int i = 0; i < 4; i++)
    t[ty + i * 8][tx] = (__bf16)w[(size_t)(bk + ty + i * 8) * DD + bn + tx];
  __syncthreads();
  #pragma unroll
  for (int i = 0; i < 4; i++)
    o[(size_t)(bn + ty + i * 8) * DD + bk + tx] = t[tx][ty + i * 8];
}

// ---------------------------------------------------------------------------
// Transpose V (bf16): v[s][col] -> o[col][s]
// ---------------------------------------------------------------------------
__global__ __launch_bounds__(256) void vtrans_k(
    const __bf16* __restrict__ v, __bf16* __restrict__ o) {
  __shared__ __bf16 t[32][33];
  int tx = threadIdx.x & 31, ty = threadIdx.x >> 5;
  int bs = blockIdx.x * 32, bc = blockIdx.y * 32;
  const __bf16* vz = v + (size_t)blockIdx.z * SS * NH;
  __bf16*       oz = o + (size_t)blockIdx.z * NH * SS;
  #pragma unroll
  for (int i = 0; i < 4; i++)
    t[ty + i * 8][tx] = vz[(size_t)(bs + ty + i * 8) * NH + bc + tx];
  __syncthreads();
  #pragma unroll
  for (int i = 0; i < 4; i++)
    oz[(size_t)(bc + ty + i * 8) * SS + bs + tx] = t[tx][ty + i * 8];
}

// ---------------------------------------------------------------------------
// Batched-operand pack: z selects (A, BT, C).
// ---------------------------------------------------------------------------
struct B3 {
  const void*  a0; const void*  a1; const void*  a2;
  const __bf16* b0; const __bf16* b1; const __bf16* b2;
  void* c0; void* c1; void* c2;
};

// ---------------------------------------------------------------------------
// ROUND 6: all-bf16 128x128 GEMM, SINGLE barrier/iter, ring-3 gl_lds staging.
//
// Round-5 diagnosis: per-iteration wall ~1500 cy vs ~300 cy of work; the
// 2-barrier + As-write->lgkmcnt->read serial chain convoyed the whole CU.
// Now BOTH operands stage via global_load_lds (A pre-converted to bf16 by
// cvt_k), so each iteration is: vmcnt(4) -> s_barrier -> issue 4 gl_lds for
// it+2 -> 8 swizzled ds_read_b128 -> 16 MFMA. No ds_write, no lgkm chain,
// half the barriers.
// Ring-3 safety: readers of slot s at iter it-1 consumed their LDS data
// before reaching barrier(it) (MFMA operands read pre-barrier); the write
// for it+2 goes to slot (it+2)%3 which was last read at it-1. Each wave's
// vmcnt(4) before barrier(it) retires its own bundle->it, so all writes to
// slot it%3 have landed before any wave exits barrier(it).
// XOR-swizzle (both sides): phys 16B-chunk c of row r holds logical seg
// c ^ ((r>>1)&3); reads use seg quad ^ ((l16>>1)&3) -> 8 slots x2 lanes,
// conflict-free.
// ---------------------------------------------------------------------------
template <typename CT>
__global__ __launch_bounds__(256, 3) void gemm_bb(B3 p) {
  __shared__ __bf16 Asr[3][128][32];   // 24 KB
  __shared__ __bf16 Bsr[3][128][32];   // 24 KB

  // XCD-chunked swizzle (nwg % 8 == 0 for all launches here).
  const unsigned nwg  = gridDim.x * gridDim.y * gridDim.z;
  const unsigned flat = blockIdx.x + gridDim.x * (blockIdx.y + gridDim.y * blockIdx.z);
  const unsigned swz  = (flat & 7) * (nwg >> 3) + (flat >> 3);
  const int bx = swz % gridDim.x;
  const unsigned rem = swz / gridDim.x;
  const int by = rem % gridDim.y;
  const int z  = rem / gridDim.y;

  const __bf16* __restrict__ A  = (const __bf16*)(z == 0 ? p.a0 : z == 1 ? p.a1 : p.a2);
  const __bf16* __restrict__ BT = z == 0 ? p.b0 : z == 1 ? p.b1 : p.b2;
  CT* __restrict__ C = (CT*)(z == 0 ? p.c0 : z == 1 ? p.c1 : p.c2);

  const int tid  = threadIdx.x;
  const int wave = tid >> 6, lane = tid & 63;
  const int quad = lane >> 4, l16 = lane & 15;
  const int wr = (wave >> 1) * 64, wc = (wave & 1) * 64;
  const int m0 = by * 128, n0 = bx * 128;

  f32x4 acc[4][4] = {};

  auto issue = [&](int it, int slot) {
    const int k0 = it * 32;
    const int rr  = lane >> 2;                     // 0..15
    const int seg = (lane & 3) ^ ((rr >> 1) & 3);  // logical seg at this phys slot
    #pragma unroll
    for (int i = 0; i < 2; i++) {
      const int row = wave * 16 + i * 64 + rr;
      gl_lds16(&A [(size_t)(m0 + row) * DD + k0 + seg * 8], &Asr[slot][wave * 16 + i * 64][0]);
      gl_lds16(&BT[(size_t)(n0 + row) * DD + k0 + seg * 8], &Bsr[slot][wave * 16 + i * 64][0]);
    }
  };

  auto compute = [&](int s) {
    bf16x8 af[4], bfr[4];
    const int ph = (quad ^ ((l16 >> 1) & 3)) * 8;
    #pragma unroll
    for (int t = 0; t < 4; t++) {
      af[t]  = *(const bf16x8*)&Asr[s][wr + t * 16 + l16][ph];
      bfr[t] = *(const bf16x8*)&Bsr[s][wc + t * 16 + l16][ph];
    }
    __builtin_amdgcn_s_setprio(1);
    #pragma unroll
    for (int mt = 0; mt < 4; mt++)
      #pragma unroll
      for (int nt = 0; nt < 4; nt++)
        acc[mt][nt] = __builtin_amdgcn_mfma_f32_16x16x32_bf16(af[mt], bfr[nt], acc[mt][nt], 0, 0, 0);
    __builtin_amdgcn_s_setprio(0);
  };

  // Prologue: bundles for iters 0 and 1 (4 gl_lds each), order-fenced.
  issue(0, 0); MEMFENCE();
  issue(1, 1); MEMFENCE();

  int cur = 0, pre = 2;   // pre = (cur+2)%3
  #pragma unroll 1
  for (int it = 0; it < 30; it++) {
    WAITVM4();                          // bundle->it landed (one bundle stays in flight)
    __builtin_amdgcn_s_barrier();
    issue(it + 2, pre);                 // flies across the next 2 iterations
    compute(cur);
    cur = cur == 2 ? 0 : cur + 1;
    pre = pre == 2 ? 0 : pre + 1;
  }
  WAITVM4(); __builtin_amdgcn_s_barrier(); compute(cur);   // it=30
  cur = cur == 2 ? 0 : cur + 1;
  WAITVM0(); __builtin_amdgcn_s_barrier(); compute(cur);   // it=31

  // Epilogue: C/D layout col=lane&15, row=quad*4+r
  #pragma unroll
  for (int mt = 0; mt < 4; mt++)
    #pragma unroll
    for (int nt = 0; nt < 4; nt++)
      #pragma unroll
      for (int r = 0; r < 4; r++) {
        int row = m0 + wr + mt * 16 + quad * 4 + r;
        int col = n0 + wc + nt * 16 + l16;
        C[(size_t)row * NH + col] = (CT)acc[mt][nt][r];
      }
}

// ---------------------------------------------------------------------------
// LEGACY fallback GEMM (round-5): fp32-or-bf16 A, 2-barrier, counted vmcnt.
// Used only when the workspace can't hold the bf16 x-copies.
// ---------------------------------------------------------------------------
template <typename AT> struct AStage;
template <> struct AStage<float>  { f32x4 d[2][2]; };
template <> struct AStage<__bf16> { bf16x8 d[2]; };

template <typename AT, typename CT>
__global__ __launch_bounds__(256, 3) void gemm_bt(B3 p, size_t aoff) {
  __shared__ __bf16 As[128][40];
  __shared__ __bf16 Bs[4][128][32];
  const unsigned nwg  = gridDim.x * gridDim.y * gridDim.z;
  const unsigned flat = blockIdx.x + gridDim.x * (blockIdx.y + gridDim.y * blockIdx.z);
  const unsigned swz  = (flat & 7) * (nwg >> 3) + (flat >> 3);
  const int bx = swz % gridDim.x;
  const unsigned rem = swz / gridDim.x;
  const int by = rem % gridDim.y;
  const int z  = rem / gridDim.y;

  const AT* __restrict__ A = (const AT*)(z == 0 ? p.a0 : z == 1 ? p.a1 : p.a2);
  const __bf16* __restrict__ BT = z == 0 ? p.b0 : z == 1 ? p.b1 : p.b2;
  CT* __restrict__ C = (CT*)(z == 0 ? p.c0 : z == 1 ? p.c1 : p.c2);

  const int tid  = threadIdx.x;
  const int wave = tid >> 6, lane = tid & 63;
  const int quad = lane >> 4, l16 = lane & 15;
  const int wr = (wave >> 1) * 64, wc = (wave & 1) * 64;
  const int m0 = by * 128, n0 = bx * 128;

  f32x4 acc[4][4] = {};
  AStage<AT> aA, aB;

  auto loadA = [&](int k0, AStage<AT>& S) {
    #pragma unroll
    for (int i = 0; i < 2; i++) {
      int c = tid + i * 256;
      int row = c >> 2, seg = (c & 3) * 8;
      if constexpr (sizeof(AT) == 4) {
        const float* ap = (const float*)A + aoff + (size_t)(m0 + row) * DD + k0 + seg;
        S.d[i][0] = *(const f32x4*)ap;
        S.d[i][1] = *(const f32x4*)(ap + 4);
      } else {
        S.d[i] = *(const bf16x8*)((const __bf16*)A + aoff + (size_t)(m0 + row) * DD + k0 + seg);
      }
    }
  };
  auto issueB = [&](int k0, int buf) {
    #pragma unroll
    for (int i = 0; i < 2; i++) {
      int rr  = lane >> 2;
      int row = wave * 16 + i * 64 + rr;
      int seg = (lane & 3) ^ ((rr >> 1) & 3);
      gl_lds16(&BT[(size_t)(n0 + row) * DD + k0 + seg * 8],
               &Bs[buf][wave * 16 + i * 64][0]);
    }
  };

  auto step = [&](int it, AStage<AT>& S, bool last, bool tail) {
    if (last) { WAITVM0(); }
    else if constexpr (sizeof(AT) == 4) { WAITVM6(); }
    else { WAITVM4(); }
    __builtin_amdgcn_s_barrier();
    #pragma unroll
    for (int i = 0; i < 2; i++) {
      int c = tid + i * 256;
      bf16x8 av;
      if constexpr (sizeof(AT) == 4) {
        #pragma unroll
        for (int j = 0; j < 4; j++) {
          av[j]     = (__bf16)S.d[i][0][j];
          av[j + 4] = (__bf16)S.d[i][1][j];
        }
      } else {
        av = S.d[i];
      }
      *(bf16x8*)&As[c >> 2][(c & 3) * 8] = av;
    }
    WAITLGKM0();
    __builtin_amdgcn_s_barrier();
    if (!tail) {
      issueB((it + 2) * 32, (it + 2) & 3);
      loadA((it + 2) * 32, S);
    }
    const int buf = it & 3;
    bf16x8 af[4], bfr[4];
    #pragma unroll
    for (int t = 0; t < 4; t++) {
      af[t]  = *(const bf16x8*)&As[wr + t * 16 + l16][quad * 8];
      bfr[t] = *(const bf16x8*)&Bs[buf][wc + t * 16 + l16][(quad ^ ((l16 >> 1) & 3)) * 8];
    }
    __builtin_amdgcn_s_setprio(1);
    #pragma unroll
    for (int mt = 0; mt < 4; mt++)
      #pragma unroll
      for (int nt = 0; nt < 4; nt++)
        acc[mt][nt] = __builtin_amdgcn_mfma_f32_16x16x32_bf16(af[mt], bfr[nt], acc[mt][nt], 0, 0, 0);
    __builtin_amdgcn_s_setprio(0);
  };

  issueB(0, 0);  loadA(0, aA);
  MEMFENCE();
  issueB(32, 1); loadA(32, aB);
  MEMFENCE();

  for (int it2 = 0; it2 < 15; it2++) {
    step(2 * it2,     aA, false, false);
    step(2 * it2 + 1, aB, false, false);
  }
  step(30, aA, false, true);
  step(31, aB, true,  true);

  #pragma unroll
  for (int mt = 0; mt < 4; mt++)
    #pragma unroll
    for (int nt = 0; nt < 4; nt++)
      #pragma unroll
      for (int r = 0; r < 4; r++) {
        int row = m0 + wr + mt * 16 + quad * 4 + r;
        int col = n0 + wc + nt * 16 + l16;
        C[(size_t)row * NH + col] = (CT)acc[mt][nt][r];
      }
}

// ---------------------------------------------------------------------------
// Pipelined causal flash attention, BK=64, swapped QK^T, register softmax,
// triangle pairing (33 tiles per block, equal-work grid) + XCD grouping.
// ---------------------------------------------------------------------------
__global__ __launch_bounds__(256, 4) void attn_k(
    const __bf16* __restrict__ Q, const __bf16* __restrict__ K,
    const __bf16* __restrict__ VT, __bf16* __restrict__ O) {
  __shared__ __bf16 Ks[64][68];   // [kpos][dh]
  __shared__ __bf16 Vs[64][68];   // [dh][kpos]

  const int tid  = threadIdx.x;
  const int wave = tid >> 6, lane = tid & 63;
  const int quad = lane >> 4, l16 = lane & 15;

  const int n    = blockIdx.x;
  const int xcd  = n & 7, slot = n >> 3;
  const int gidx = xcd + 8 * (slot >> 4);   // (h,z) group id
  const int bx   = slot & 15;               // pair index 0..15
  const int h = gidx & 15, z = gidx >> 4;

  const __bf16* Qg = Q + (size_t)z * SS * NH + h * DHE;      // [s][dh] stride NH
  const __bf16* Kg = K + (size_t)z * SS * NH + h * DHE;
  const __bf16* Vg = VT + ((size_t)z * HH + h) * DHE * SS;   // [dh][s]
  __bf16*       Og = O + (size_t)z * SS * NH + h * DHE;

  bf16x8 kreg[2], vreg[2];
  auto loadKV = [&](int k0) {
    #pragma unroll
    for (int i = 0; i < 2; i++) {
      int v = tid + i * 256;   // 0..511 chunks of 8 elems = 64x64 tile
      kreg[i] = *(const bf16x8*)&Kg[(size_t)(k0 + (v >> 3)) * NH + (v & 7) * 8];
      vreg[i] = *(const bf16x8*)&Vg[(size_t)(v >> 3) * SS + k0 + (v & 7) * 8];
    }
  };

  #pragma unroll 1
  for (int seg = 0; seg < 2; seg++) {
    const int qt = seg ? bx : 31 - bx;       // {16..31} then {0..15}
    const int q0 = qt * 64;
    const int ntiles = qt + 1;

    const int qrow = q0 + wave * 16 + l16;
    bf16x8 qf[2];
    #pragma unroll
    for (int kk = 0; kk < 2; kk++) {
      bf16x8 t = *(const bf16x8*)&Qg[(size_t)qrow * NH + kk * 32 + quad * 8];
      #pragma unroll
      for (int j = 0; j < 8; j++) t[j] = (__bf16)((float)t[j] * 0.125f);
      qf[kk] = t;
    }

    loadKV(0);
    float prows = 0.f;
    f32x4 oacc[4] = {};

    for (int kt = 0; kt < ntiles; kt++) {
      const int k0 = kt * 64;
      __syncthreads();
      #pragma unroll
      for (int i = 0; i < 2; i++) {
        int v = tid + i * 256;
        *(bf16x8*)&Ks[v >> 3][(v & 7) * 8] = kreg[i];
        *(bf16x8*)&Vs[v >> 3][(v & 7) * 8] = vreg[i];
      }
      __syncthreads();
      if (kt + 1 < ntiles) loadKV(k0 + 64);

      const bool diag = (kt == ntiles - 1);
      const int nq  = diag ? wave + 1 : 4;
      const int nsm = diag ? ((wave + 2) & ~1) : 4;
      const int nkk = nsm >> 1;

      f32x4 sc[4] = {};
      __builtin_amdgcn_s_setprio(1);
      #pragma unroll
      for (int kk = 0; kk < 2; kk++)
        #pragma unroll
        for (int nt = 0; nt < 4; nt++)
          if (nt < nq) {
            bf16x8 kf = *(const bf16x8*)&Ks[nt * 16 + l16][kk * 32 + quad * 8];
            sc[nt] = __builtin_amdgcn_mfma_f32_16x16x32_bf16(kf, qf[kk], sc[nt], 0, 0, 0);
          }
      __builtin_amdgcn_s_setprio(0);

      bf16x8 pf[2];
      #pragma unroll
      for (int t = 0; t < 2; t++)
        if (t < nkk) {
          const int nt0 = 2 * t, nt1 = 2 * t + 1;
          float pA[4], pB[4];
          #pragma unroll
          for (int r = 0; r < 4; r++) {
            float v0 = sc[nt0][r], v1 = sc[nt1][r];
            if (diag) {
              const int kb = k0 + quad * 4 + r;
              if (kb + nt0 * 16 > qrow) v0 = NEG_BIG;
              if (kb + nt1 * 16 > qrow) v1 = NEG_BIG;
            }
            pA[r] = __expf(v0); pB[r] = __expf(v1);
            prows += pA[r] + pB[r];
          }
          unsigned a0 = pack_bf2(pA[0], pA[1]), a1 = pack_bf2(pA[2], pA[3]);
          unsigned b0 = pack_bf2(pB[0], pB[1]), b1 = pack_bf2(pB[2], pB[3]);
          unsigned x0 = (quad & 1) ? a0 : b0, x1 = (quad & 1) ? a1 : b1;
          unsigned y0 = (quad & 1) ? b0 : a0, y1 = (quad & 1) ? b1 : a1;
          unsigned r16_0 = __shfl_xor((int)x0, 16), r16_1 = __shfl_xor((int)x1, 16);
          unsigned r32_0 = __shfl_xor((int)x0, 32), r32_1 = __shfl_xor((int)x1, 32);
          unsigned r48_0 = __shfl_xor((int)y0, 48), r48_1 = __shfl_xor((int)y1, 48);
          unsigned w0 = quad == 0 ? a0    : quad == 1 ? r48_0 : quad == 2 ? r32_0 : r16_0;
          unsigned w1 = quad == 0 ? a1    : quad == 1 ? r48_1 : quad == 2 ? r32_1 : r16_1;
          unsigned w2 = quad == 0 ? r16_0 : quad == 1 ? r32_0 : quad == 2 ? r48_0 : b0;
          unsigned w3 = quad == 0 ? r16_1 : quad == 1 ? r32_1 : quad == 2 ? r48_1 : b1;
          union { unsigned u[4]; bf16x8 v; } asm_;
          asm_.u[0] = w0; asm_.u[1] = w1; asm_.u[2] = w2; asm_.u[3] = w3;
          pf[t] = asm_.v;
        }

      __builtin_amdgcn_s_setprio(1);
      #pragma unroll
      for (int kk = 0; kk < 2; kk++)
        if (kk < nkk) {
          #pragma unroll
          for (int dt = 0; dt < 4; dt++) {
            bf16x8 vf = *(const bf16x8*)&Vs[dt * 16 + l16][kk * 32 + quad * 8];
            oacc[dt] = __builtin_amdgcn_mfma_f32_16x16x32_bf16(pf[kk], vf, oacc[dt], 0, 0, 0);
          }
        }
      __builtin_amdgcn_s_setprio(0);
    }

    prows += __shfl_xor(prows, 16, 64);
    prows += __shfl_xor(prows, 32, 64);

    #pragma unroll
    for (int r = 0; r < 4; r++) {
      float tot = __shfl(prows, quad * 4 + r, 64);
      float inv = tot > 0.f ? 1.0f / tot : 0.f;
      int qg = q0 + wave * 16 + quad * 4 + r;
      #pragma unroll
      for (int dt = 0; dt < 4; dt++)
        Og[(size_t)qg * NH + dt * 16 + l16] = (__bf16)(oacc[dt][r] * inv);
    }
  }
}

// ---------------------------------------------------------------------------
extern "C" void kernel_launch(void* const* d_in, const int* in_sizes, int n_in,
                              void* d_out, int out_size, void* d_ws, size_t ws_size,
                              hipStream_t stream) {
  const float* x_q = (const float*)d_in[0];
  const float* x_k = (const float*)d_in[1];
  const float* x_v = (const float*)d_in[2];
  // d_in[3] = causal mask — statically known, unused
  const float* Wq = (const float*)d_in[4];
  const float* Wk = (const float*)d_in[5];
  const float* Wv = (const float*)d_in[6];
  const float* Wo = (const float*)d_in[7];
  float* out = (float*)d_out;

  const size_t WTE = (size_t)DD * NH;           // 1M elems per weight
  const size_t PB  = (size_t)SS * NH;           // per-batch elems (2M)
  const size_t FULLB = (size_t)BB * PB;         // 8M elems

  char* ws = (char*)d_ws;
  __bf16* WqT = (__bf16*)ws;
  __bf16* WkT = WqT + WTE;
  __bf16* WvT = WkT + WTE;
  __bf16* WoT = WvT + WTE;
  __bf16* buf0 = WoT + WTE;                     // after 8 MB of weights

  wtrans_k<<<dim3(32, 32, 4), 256, 0, stream>>>(Wq, Wk, Wv, Wo, WqT, WkT, WvT, WoT);

  const size_t needFast = 4 * WTE * 2 + 4 * FULLB * 2 + 3 * FULLB * 2;  // 120 MB
  const size_t needFull = 4 * WTE * 2 + 4 * FULLB * 2;                  // 72 MB
  if (ws_size >= needFast) {
    __bf16* Qb  = buf0;
    __bf16* Kb  = Qb + FULLB;
    __bf16* Vb  = Kb + FULLB;
    __bf16* VT  = Vb + FULLB;
    __bf16* xqb = VT + FULLB;
    __bf16* xkb = xqb + FULLB;
    __bf16* xvb = xkb + FULLB;
    __bf16* Ob  = Vb;                 // alias: Ob reuses Vb slot
    cvt_k<<<dim3(1024, 1, 3), 256, 0, stream>>>(x_q, x_k, x_v, xqb, xkb, xvb);
    B3 qkv = { xqb, xkb, xvb, WqT, WkT, WvT, Qb, Kb, Vb };
    gemm_bb<__bf16><<<dim3(8, 64, 3), 256, 0, stream>>>(qkv);
    vtrans_k<<<dim3(SS / 32, NH / 32, BB), 256, 0, stream>>>(Vb, VT);
    attn_k<<<dim3((SS / 128) * HH * BB), 256, 0, stream>>>(Qb, Kb, VT, Ob);
    B3 og = { Ob, Ob, Ob, WoT, WoT, WoT, out, out, out };
    gemm_bb<float><<<dim3(8, 64, 1), 256, 0, stream>>>(og);
  } else if (ws_size >= needFull) {
    __bf16* Qb = buf0;
    __bf16* Kb = Qb + FULLB;
    __bf16* Vb = Kb + FULLB;
    __bf16* VT = Vb + FULLB;
    __bf16* Ob = Vb;                  // alias
    B3 qkv = { x_q, x_k, x_v, WqT, WkT, WvT, Qb, Kb, Vb };
    gemm_bt<float, __bf16><<<dim3(8, 64, 3), 256, 0, stream>>>(qkv, 0);
    vtrans_k<<<dim3(SS / 32, NH / 32, BB), 256, 0, stream>>>(Vb, VT);
    attn_k<<<dim3((SS / 128) * HH * BB), 256, 0, stream>>>(Qb, Kb, VT, Ob);
    B3 og = { Ob, Ob, Ob, WoT, WoT, WoT, out, out, out };
    gemm_bt<__bf16, float><<<dim3(8, 64, 1), 256, 0, stream>>>(og, 0);
  } else {
    __bf16* Qb = buf0;
    __bf16* Kb = Qb + PB;
    __bf16* Vb = Kb + PB;
    __bf16* VT = Vb + PB;
    __bf16* Ob = Vb;                  // alias
    for (int b = 0; b < BB; b++) {
      const size_t boff = (size_t)b * PB;
      B3 qkv = { x_q, x_k, x_v, WqT, WkT, WvT, Qb, Kb, Vb };
      gemm_bt<float, __bf16><<<dim3(8, 16, 3), 256, 0, stream>>>(qkv, boff);
      vtrans_k<<<dim3(SS / 32, NH / 32, 1), 256, 0, stream>>>(Vb, VT);
      attn_k<<<dim3((SS / 128) * HH), 256, 0, stream>>>(Qb, Kb, VT, Ob);
      B3 og = { Ob, Ob, Ob, WoT, WoT, WoT, out + boff, out + boff, out + boff };
      gemm_bt<__bf16, float><<<dim3(8, 16, 1), 256, 0, stream>>>(og, 0);
    }
  }
}